// Round 1
// 1071.405 us; speedup vs baseline: 1.2470x; 1.2470x over previous
//
#include <hip/hip_runtime.h>
#include <math.h>

// Problem constants
#define BB 8
#define TT 512
#define DD 768
#define HH 8
#define HDIM 96

typedef short s16x8 __attribute__((ext_vector_type(8)));
typedef float f32x4 __attribute__((ext_vector_type(4)));

__device__ inline unsigned short f2bf(float f) {
    union { float f; unsigned u; } v; v.f = f;
    unsigned u = v.u;
    unsigned r = (u + 0x7fffu + ((u >> 16) & 1u)) >> 16;
    return (unsigned short)r;
}

__device__ inline float gelu_exact(float x) {
    return 0.5f * x * (1.0f + erff(x * 0.70710678118654752440f));
}

// ---------------------------------------------------------------------------
// Generic batched GEMM: C[z] = alpha * A[z] * op(B[z]) (+bias) (gelu?) (+resid)
//   A is [M,K] row-major, lda
//   TRANSB=1: B is [N,K] row-major (ldb over n)  -> C = A * B^T
//   TRANSB=0: B is [K,N] row-major (ldb over k)  -> C = A * B
//   z = zb*Hd + zh;  A off = zb*sAb + zh*sAh;  B off = bidx? bidx[zb]*sBexp : 0
//                     plus zb*sBb + zh*sBh;  C off = zb*sCb + zh*sCh
// Block tile 64x64, K-tile 32, 4 waves each computing 32x32 via 2x2 MFMA 16x16x32.
// ---------------------------------------------------------------------------
template<int TRANSB>
__global__ __launch_bounds__(256) void gemm_kernel(
    const float* __restrict__ A, long long sAb, long long sAh, int lda,
    const float* __restrict__ Bmat, long long sBb, long long sBh, int ldb,
    const int* __restrict__ bidx, long long sBexp,
    float* __restrict__ C, long long sCb, long long sCh, int ldc,
    const float* __restrict__ bias, long long sBiasExp,
    const float* __restrict__ resid, long long sResB, int ldr,
    float alpha, int act, int M, int N, int K, int Hd)
{
    int z = blockIdx.z;
    int zb = z / Hd;
    int zh = z - zb * Hd;
    const float* Ab = A + zb * sAb + zh * sAh;
    long long boff = zb * sBb + zh * sBh;
    if (bidx) boff += (long long)bidx[zb] * sBexp;
    const float* Bb = Bmat + boff;
    float* Cb = C + zb * sCb + zh * sCh;
    const float* biasb = bias ? (bias + (bidx ? (long long)bidx[zb] * sBiasExp : 0)) : nullptr;
    const float* residb = resid ? (resid + zb * sResB) : nullptr;

    int n0 = blockIdx.x * 64;
    int m0 = blockIdx.y * 64;

    // LDS tiles: 64 rows x 32 bf16, row stride 40 shorts (80 B: 16B-aligned, 2-way banks)
    __shared__ __align__(16) unsigned short As[64 * 40];
    __shared__ __align__(16) unsigned short Bs[64 * 40];

    int tid = threadIdx.x;
    int wave = tid >> 6;
    int lane = tid & 63;
    int wi = wave & 1, wj = wave >> 1;
    int lrow = lane & 15;
    int lk = (lane >> 4) * 8;

    f32x4 acc[2][2];
    #pragma unroll
    for (int i = 0; i < 2; i++)
        #pragma unroll
        for (int j = 0; j < 2; j++)
            acc[i][j] = (f32x4){0.f, 0.f, 0.f, 0.f};

    int nK = K >> 5;
    for (int kt = 0; kt < nK; ++kt) {
        int k0 = kt << 5;
        __syncthreads();
        // stage A: 64x32 f32 -> bf16. slot s: row=s>>3, col=(s&7)*4
        #pragma unroll
        for (int half = 0; half < 2; ++half) {
            int s = tid + half * 256;
            int r = s >> 3, cs = (s & 7) * 4;
            const float* src = Ab + (long long)(m0 + r) * lda + k0 + cs;
            float4 v = *(const float4*)src;
            unsigned short* dst = &As[r * 40 + cs];
            dst[0] = f2bf(v.x); dst[1] = f2bf(v.y); dst[2] = f2bf(v.z); dst[3] = f2bf(v.w);
        }
        if (TRANSB) {
            #pragma unroll
            for (int half = 0; half < 2; ++half) {
                int s = tid + half * 256;
                int r = s >> 3, cs = (s & 7) * 4;
                int n = n0 + r;
                unsigned short* dst = &Bs[r * 40 + cs];
                if (n < N) {
                    const float* src = Bb + (long long)n * ldb + k0 + cs;
                    float4 v = *(const float4*)src;
                    dst[0] = f2bf(v.x); dst[1] = f2bf(v.y); dst[2] = f2bf(v.z); dst[3] = f2bf(v.w);
                } else {
                    dst[0] = 0; dst[1] = 0; dst[2] = 0; dst[3] = 0;
                }
            }
        } else {
            // B[k][n] -> Bs[n][k] transpose-on-stage. slot s: k=s>>4, n=(s&15)*4
            #pragma unroll
            for (int half = 0; half < 2; ++half) {
                int s = tid + half * 256;
                int k = s >> 4, ns = (s & 15) * 4;
                const float* src = Bb + (long long)(k0 + k) * ldb + n0 + ns;
                #pragma unroll
                for (int j = 0; j < 4; ++j) {
                    float v = (n0 + ns + j < N) ? src[j] : 0.0f;
                    Bs[(ns + j) * 40 + k] = f2bf(v);
                }
            }
        }
        __syncthreads();

        s16x8 afrag[2], bfrag[2];
        #pragma unroll
        for (int i = 0; i < 2; i++)
            afrag[i] = *(const s16x8*)&As[(wi * 32 + i * 16 + lrow) * 40 + lk];
        #pragma unroll
        for (int j = 0; j < 2; j++)
            bfrag[j] = *(const s16x8*)&Bs[(wj * 32 + j * 16 + lrow) * 40 + lk];
        #pragma unroll
        for (int i = 0; i < 2; i++)
            #pragma unroll
            for (int j = 0; j < 2; j++)
                acc[i][j] = __builtin_amdgcn_mfma_f32_16x16x32_bf16(afrag[i], bfrag[j], acc[i][j], 0, 0, 0);
    }

    // epilogue: C/D layout col=lane&15, row=(lane>>4)*4+reg
    int col16 = lane & 15;
    int rquad = (lane >> 4) * 4;
    #pragma unroll
    for (int i = 0; i < 2; i++) {
        #pragma unroll
        for (int j = 0; j < 2; j++) {
            int n = n0 + wj * 32 + j * 16 + col16;
            if (n >= N) continue;
            float bv = biasb ? biasb[n] : 0.0f;
            #pragma unroll
            for (int r = 0; r < 4; r++) {
                int m = m0 + wi * 32 + i * 16 + rquad + r;
                float v = alpha * acc[i][j][r] + bv;
                if (act == 1) v = gelu_exact(v);
                if (residb) v += residb[(long long)m * ldr + n];
                Cb[(long long)m * ldc + n] = v;
            }
        }
    }
}

// ---------------------------------------------------------------------------
// Fused flash attention: O = softmax(scale * Q K^T [causal]) V  per (b,h).
// QKV packed [B][T][3*D], q|k|v at col 0|D|2D, head h at col offset h*96.
// Grid (T/64, B*H), 256 threads = 4 waves, each wave owns 16 query rows.
// Full 64x512 score strip lives in registers (acc[32] f32x4 per lane),
// softmax is wave-parallel (shfl_xor within 16-lane col groups),
// PV transposes P through a small per-tile LDS buffer (unnormalized e,
// normalized by 1/rowsum in the epilogue).
// ---------------------------------------------------------------------------
__global__ __launch_bounds__(256, 2) void attn_kernel(
    const float* __restrict__ QKV, float* __restrict__ Out,
    int causal, float scale)
{
    int qt = blockIdx.x;
    int bh = blockIdx.y;
    int b = bh >> 3;
    int h = bh & 7;
    const float* Qb = QKV + (long long)b * TT * 3 * DD + (long long)h * HDIM;
    const float* Kb = Qb + DD;
    const float* Vb = Qb + 2 * DD;
    float* Ob = Out + (long long)b * TT * DD + (long long)h * HDIM;

    // row strides (shorts): 104 (=208B, 16B-aligned) and 72 (=144B, 16B-aligned)
    __shared__ __align__(16) unsigned short Qs[64 * 104];  // 13.0 KB  [qrow][d]
    __shared__ __align__(16) unsigned short Ks[64 * 104];  // 13.0 KB  [krow][d]
    __shared__ __align__(16) unsigned short Vs[96 * 72];   // 13.5 KB  [d][krow]
    __shared__ __align__(16) unsigned short Ps[64 * 72];   // 9.0 KB   [qrow][krow]

    int tid = threadIdx.x;
    int wave = tid >> 6;
    int lane = tid & 63;
    int col16 = lane & 15;
    int lkg = lane >> 4;       // 0..3
    int lk = lkg * 8;
    int m0 = qt * 64;

    // ---- stage Q tile 64x96 f32 -> bf16 (1536 float4 slots, 6/thread) ----
    #pragma unroll
    for (int it = 0; it < 6; ++it) {
        int s = tid + it * 256;
        int r = s / 24, c4 = (s % 24) * 4;
        float4 v = *(const float4*)(Qb + (long long)(m0 + r) * (3 * DD) + c4);
        unsigned short* dst = &Qs[r * 104 + c4];
        dst[0] = f2bf(v.x); dst[1] = f2bf(v.y); dst[2] = f2bf(v.z); dst[3] = f2bf(v.w);
    }
    __syncthreads();

    // Q A-frags for this wave's 16 rows (rows wave*16 + (lane&15)), K=96 -> 3 frags
    s16x8 qf[3];
    #pragma unroll
    for (int kk = 0; kk < 3; ++kk)
        qf[kk] = *(const s16x8*)&Qs[(wave * 16 + col16) * 104 + kk * 32 + lk];

    // ---- QK^T: acc[n] holds S[row = wave*16+lkg*4+r][col = n*16+col16] ----
    f32x4 acc[32];
    #pragma unroll
    for (int n = 0; n < 32; ++n) acc[n] = (f32x4){0.f, 0.f, 0.f, 0.f};

    #pragma unroll
    for (int kt = 0; kt < 8; ++kt) {
        // stage K tile 64x96
        #pragma unroll
        for (int it = 0; it < 6; ++it) {
            int s = tid + it * 256;
            int r = s / 24, c4 = (s % 24) * 4;
            float4 v = *(const float4*)(Kb + (long long)(kt * 64 + r) * (3 * DD) + c4);
            unsigned short* dst = &Ks[r * 104 + c4];
            dst[0] = f2bf(v.x); dst[1] = f2bf(v.y); dst[2] = f2bf(v.z); dst[3] = f2bf(v.w);
        }
        __syncthreads();
        #pragma unroll
        for (int kk = 0; kk < 3; ++kk) {
            #pragma unroll
            for (int j = 0; j < 4; ++j) {
                s16x8 bf = *(const s16x8*)&Ks[(j * 16 + col16) * 104 + kk * 32 + lk];
                acc[kt * 4 + j] = __builtin_amdgcn_mfma_f32_16x16x32_bf16(qf[kk], bf, acc[kt * 4 + j], 0, 0, 0);
            }
        }
        __syncthreads();
    }

    // ---- softmax (registers + shfl only) ----
    int rowbase = m0 + wave * 16 + lkg * 4;  // + r
    float mx[4];
    #pragma unroll
    for (int r = 0; r < 4; ++r) mx[r] = -3.0e38f;
    #pragma unroll
    for (int n = 0; n < 32; ++n) {
        int colg = n * 16 + col16;
        #pragma unroll
        for (int r = 0; r < 4; ++r) {
            float v = acc[n][r] * scale;
            if (causal && colg > rowbase + r) v = -3.0e38f;
            acc[n][r] = v;
            mx[r] = fmaxf(mx[r], v);
        }
    }
    #pragma unroll
    for (int m = 1; m <= 8; m <<= 1)
        #pragma unroll
        for (int r = 0; r < 4; ++r)
            mx[r] = fmaxf(mx[r], __shfl_xor(mx[r], m, 64));

    float sum[4] = {0.f, 0.f, 0.f, 0.f};
    #pragma unroll
    for (int n = 0; n < 32; ++n) {
        #pragma unroll
        for (int r = 0; r < 4; ++r) {
            float e = __expf(acc[n][r] - mx[r]);
            acc[n][r] = e;
            sum[r] += e;
        }
    }
    #pragma unroll
    for (int m = 1; m <= 8; m <<= 1)
        #pragma unroll
        for (int r = 0; r < 4; ++r)
            sum[r] += __shfl_xor(sum[r], m, 64);
    float inv[4];
    #pragma unroll
    for (int r = 0; r < 4; ++r) inv[r] = 1.0f / sum[r];

    // ---- PV: O[64x96] += P[64x64 per tile] * V[64x96 per tile] ----
    f32x4 oacc[6];
    #pragma unroll
    for (int j = 0; j < 6; ++j) oacc[j] = (f32x4){0.f, 0.f, 0.f, 0.f};

    #pragma unroll
    for (int kt = 0; kt < 8; ++kt) {
        __syncthreads();  // prior MFMA reads of Ps/Vs done
        // write P strip for this key tile (unnormalized e, bf16)
        #pragma unroll
        for (int j = 0; j < 4; ++j) {
            #pragma unroll
            for (int r = 0; r < 4; ++r)
                Ps[(wave * 16 + lkg * 4 + r) * 72 + j * 16 + col16] = f2bf(acc[kt * 4 + j][r]);
        }
        // stage V tile transposed: V[kt*64+key][d] -> Vs[d][key]
        #pragma unroll
        for (int it = 0; it < 6; ++it) {
            int s = tid + it * 256;
            int key = s / 24, c4 = (s % 24) * 4;
            float4 v = *(const float4*)(Vb + (long long)(kt * 64 + key) * (3 * DD) + c4);
            Vs[(c4 + 0) * 72 + key] = f2bf(v.x);
            Vs[(c4 + 1) * 72 + key] = f2bf(v.y);
            Vs[(c4 + 2) * 72 + key] = f2bf(v.z);
            Vs[(c4 + 3) * 72 + key] = f2bf(v.w);
        }
        __syncthreads();
        #pragma unroll
        for (int kk = 0; kk < 2; ++kk) {
            s16x8 pf = *(const s16x8*)&Ps[(wave * 16 + col16) * 72 + kk * 32 + lk];
            #pragma unroll
            for (int j = 0; j < 6; ++j) {
                s16x8 vf = *(const s16x8*)&Vs[(j * 16 + col16) * 72 + kk * 32 + lk];
                oacc[j] = __builtin_amdgcn_mfma_f32_16x16x32_bf16(pf, vf, oacc[j], 0, 0, 0);
            }
        }
    }

    // ---- epilogue: normalize and store ----
    int rquad = lkg * 4;
    #pragma unroll
    for (int j = 0; j < 6; ++j) {
        int d = j * 16 + col16;
        #pragma unroll
        for (int r = 0; r < 4; ++r) {
            int row = m0 + wave * 16 + rquad + r;
            Ob[(long long)row * DD + d] = oacc[j][r] * inv[r];
        }
    }
}

// ---------------------------------------------------------------------------
// LayerNorm over last dim (768). One block per row.
// ---------------------------------------------------------------------------
__global__ __launch_bounds__(256) void ln_kernel(
    const float* __restrict__ x, const float* __restrict__ g,
    const float* __restrict__ b, float* __restrict__ out)
{
    long long row = blockIdx.x;
    const float* xr = x + row * DD;
    float* orow = out + row * DD;
    int t = threadIdx.x;
    float vals[3];
    float s = 0.f, ss = 0.f;
    #pragma unroll
    for (int i = 0; i < 3; i++) {
        float v = xr[t + i * 256];
        vals[i] = v; s += v; ss += v * v;
    }
    __shared__ float rs[256], rss[256];
    rs[t] = s; rss[t] = ss; __syncthreads();
    for (int k = 128; k > 0; k >>= 1) {
        if (t < k) { rs[t] += rs[t + k]; rss[t] += rss[t + k]; }
        __syncthreads();
    }
    float mean = rs[0] * (1.0f / DD);
    float var = rss[0] * (1.0f / DD) - mean * mean;
    float inv = rsqrtf(var + 1e-5f);
    #pragma unroll
    for (int i = 0; i < 3; i++) {
        int d = t + i * 256;
        orow[d] = (vals[i] - mean) * inv * g[d] + b[d];
    }
}

// ---------------------------------------------------------------------------
// Router part 1: partial column sums of x over T (x.mean(1) numerator).
// grid (B, 3, 8), block 256. part layout [B][8][768]
// ---------------------------------------------------------------------------
__global__ __launch_bounds__(256) void mean_part_kernel(
    const float* __restrict__ x, float* __restrict__ part)
{
    int b = blockIdx.x, dseg = blockIdx.y, rc = blockIdx.z;
    int d = dseg * 256 + threadIdx.x;
    const float* xb = x + (long long)b * TT * DD;
    float s = 0.f;
    int r0 = rc * 64;
    for (int r = r0; r < r0 + 64; ++r) s += xb[(long long)r * DD + d];
    part[((long long)b * 8 + rc) * DD + d] = s;
}

// ---------------------------------------------------------------------------
// Router part 2: mean -> gelu(mean@W1^T+b1) -> logits -> segment argmax.
// grid (B), block 128. idx[0..7]=idx_s, idx[8..15]=idx_t
// ---------------------------------------------------------------------------
__global__ __launch_bounds__(128) void router_kernel(
    const float* __restrict__ part, const float* __restrict__ w1,
    const float* __restrict__ b1, const float* __restrict__ w2,
    const float* __restrict__ b2, int* __restrict__ idx)
{
    int b = blockIdx.x, t = threadIdx.x;
    __shared__ float xm[DD];
    __shared__ float h[128];
    __shared__ float logits[8];
    for (int i = t; i < DD; i += 128) {
        float s = 0.f;
        for (int rc = 0; rc < 8; ++rc) s += part[((long long)b * 8 + rc) * DD + i];
        xm[i] = s * (1.0f / TT);
    }
    __syncthreads();
    {
        float s = b1[t];
        const float* w = w1 + (long long)t * DD;
        for (int d = 0; d < DD; ++d) s += xm[d] * w[d];
        h[t] = gelu_exact(s);
    }
    __syncthreads();
    if (t < 8) {
        float s = b2[t];
        const float* w = w2 + t * 128;
        for (int d = 0; d < 128; ++d) s += h[d] * w[d];
        logits[t] = s;
    }
    __syncthreads();
    if (t == 0) {
        int bsix = 0;
        for (int i = 1; i < 4; i++) if (logits[i] > logits[bsix]) bsix = i;
        int btix = 4;
        for (int i = 5; i < 8; i++) if (logits[i] > logits[btix]) btix = i;
        idx[b] = bsix;
        idx[b + BB] = btix - 4;
    }
}

// ---------------------------------------------------------------------------
static void run_gemm(hipStream_t stream, int transb,
    const float* A, long long sAb, long long sAh, int lda,
    const float* Bmat, long long sBb, long long sBh, int ldb,
    const int* bidx, long long sBexp,
    float* C, long long sCb, long long sCh, int ldc,
    const float* bias, long long sBiasExp,
    const float* resid, long long sResB, int ldr,
    float alpha, int act, int M, int N, int K, int Hd, int batchB)
{
    dim3 grid((N + 63) / 64, (M + 63) / 64, batchB * Hd);
    if (transb)
        gemm_kernel<1><<<grid, 256, 0, stream>>>(A, sAb, sAh, lda, Bmat, sBb, sBh, ldb,
            bidx, sBexp, C, sCb, sCh, ldc, bias, sBiasExp, resid, sResB, ldr,
            alpha, act, M, N, K, Hd);
    else
        gemm_kernel<0><<<grid, 256, 0, stream>>>(A, sAb, sAh, lda, Bmat, sBb, sBh, ldb,
            bidx, sBexp, C, sCb, sCh, ldc, bias, sBiasExp, resid, sResB, ldr,
            alpha, act, M, N, K, Hd);
}

extern "C" void kernel_launch(void* const* d_in, const int* in_sizes, int n_in,
                              void* d_out, int out_size, void* d_ws, size_t ws_size,
                              hipStream_t stream)
{
    const float* x       = (const float*)d_in[0];
    const float* rw1     = (const float*)d_in[1];
    const float* rb1     = (const float*)d_in[2];
    const float* rw2     = (const float*)d_in[3];
    const float* rb2     = (const float*)d_in[4];
    const float* gs      = (const float*)d_in[5];
    const float* bs      = (const float*)d_in[6];
    const float* gt      = (const float*)d_in[7];
    const float* btt     = (const float*)d_in[8];
    const float* gm      = (const float*)d_in[9];
    const float* bm      = (const float*)d_in[10];
    const float* sp_wqkv = (const float*)d_in[11];
    const float* sp_bqkv = (const float*)d_in[12];
    const float* sp_wo   = (const float*)d_in[13];
    const float* sp_bo   = (const float*)d_in[14];
    const float* tp_wq   = (const float*)d_in[15];
    const float* tp_bq   = (const float*)d_in[16];
    const float* tp_wk   = (const float*)d_in[17];
    const float* tp_bk   = (const float*)d_in[18];
    const float* tp_wv   = (const float*)d_in[19];
    const float* tp_bv   = (const float*)d_in[20];
    const float* tp_wo   = (const float*)d_in[21];
    const float* tp_bo   = (const float*)d_in[22];
    const float* c_wqkv  = (const float*)d_in[23];
    const float* c_bqkv  = (const float*)d_in[24];
    const float* c_wo    = (const float*)d_in[25];
    const float* c_bo    = (const float*)d_in[26];
    const float* m_w1    = (const float*)d_in[27];
    const float* m_b1    = (const float*)d_in[28];
    const float* m_w2    = (const float*)d_in[29];
    const float* m_b2    = (const float*)d_in[30];
    float* out = (float*)d_out;

    float* ws = (float*)d_ws;
    size_t o = 0;
    float* part  = ws + o; o += (size_t)BB * 8 * DD;
    int*   idx   = (int*)(ws + o); o += 16;
    float* xn    = ws + o; o += (size_t)4096 * DD;   // LN outputs (xn_s, then xt, then x1)
    float* tmp1  = ws + o; o += (size_t)4096 * DD;   // attention outputs
    float* tmp2  = ws + o; o += (size_t)4096 * DD;   // LN for mlp
    float* soutb = ws + o; o += (size_t)4096 * DD;   // spatial_out
    float* toutb = ws + o; o += (size_t)4096 * DD;   // temporal_out
    float* x1b   = ws + o; o += (size_t)4096 * DD;   // x + fused
    float* qkvb  = ws + o; o += (size_t)4096 * 2304; // q|k|v packed, ldc=2304
    float* Sb    = ws + o; o += (size_t)64 * TT * TT; // mlp hidden y (scores now fused)

    int* idx_s = idx;
    int* idx_t = idx + BB;

    const long long sTD  = (long long)TT * DD;       // 512*768
    const long long sT3D = (long long)TT * 3 * DD;   // 512*2304
    const float qk_scale = 1.0f / sqrtf((float)HDIM);

    // ---- router ----
    mean_part_kernel<<<dim3(BB, 3, 8), 256, 0, stream>>>(x, part);
    router_kernel<<<BB, 128, 0, stream>>>(part, rw1, rb1, rw2, rb2, idx);

    // ---- spatial branch ----
    ln_kernel<<<4096, 256, 0, stream>>>(x, gs, bs, xn);
    // qkv = xn @ sp_wqkv[idx_s]^T + sp_bqkv[idx_s]
    run_gemm(stream, 1, xn, sTD, 0, DD, sp_wqkv, 0, 0, DD, idx_s, (long long)3 * DD * DD,
             qkvb, sT3D, 0, 3 * DD, sp_bqkv, 3 * DD, nullptr, 0, 0,
             1.0f, 0, TT, 3 * DD, DD, 1, BB);
    // fused attention: tmp1 = softmax(scale*QK^T) V   per (b,h)
    attn_kernel<<<dim3(TT / 64, BB * HH), 256, 0, stream>>>(qkvb, tmp1, 0, qk_scale);
    // spatial_out = O @ sp_wo[idx_s]^T + sp_bo[idx_s]
    run_gemm(stream, 1, tmp1, sTD, 0, DD, sp_wo, 0, 0, DD, idx_s, (long long)DD * DD,
             soutb, sTD, 0, DD, sp_bo, DD, nullptr, 0, 0,
             1.0f, 0, TT, DD, DD, 1, BB);

    // ---- temporal branch ----
    ln_kernel<<<4096, 256, 0, stream>>>(x, gt, btt, xn);
    run_gemm(stream, 1, xn, sTD, 0, DD, tp_wq, 0, 0, DD, idx_t, (long long)DD * DD,
             qkvb, sT3D, 0, 3 * DD, tp_bq, DD, nullptr, 0, 0,
             1.0f, 0, TT, DD, DD, 1, BB);
    run_gemm(stream, 1, xn, sTD, 0, DD, tp_wk, 0, 0, DD, idx_t, (long long)DD * DD,
             qkvb + DD, sT3D, 0, 3 * DD, tp_bk, DD, nullptr, 0, 0,
             1.0f, 0, TT, DD, DD, 1, BB);
    run_gemm(stream, 1, xn, sTD, 0, DD, tp_wv, 0, 0, DD, idx_t, (long long)DD * DD,
             qkvb + 2 * DD, sT3D, 0, 3 * DD, tp_bv, DD, nullptr, 0, 0,
             1.0f, 0, TT, DD, DD, 1, BB);
    // fused causal attention
    attn_kernel<<<dim3(TT / 64, BB * HH), 256, 0, stream>>>(qkvb, tmp1, 1, qk_scale);
    // temporal_out = xt + O @ tp_wo[idx_t]^T + tp_bo[idx_t]
    run_gemm(stream, 1, tmp1, sTD, 0, DD, tp_wo, 0, 0, DD, idx_t, (long long)DD * DD,
             toutb, sTD, 0, DD, tp_bo, DD, xn, sTD, DD,
             1.0f, 0, TT, DD, DD, 1, BB);

    // ---- cross attention ----
    // cq = spatial_out @ Wq^T + bq  (rows 0..768 of cross_wqkv)
    run_gemm(stream, 1, soutb, sTD, 0, DD, c_wqkv, 0, 0, DD, nullptr, 0,
             qkvb, sT3D, 0, 3 * DD, c_bqkv, 0, nullptr, 0, 0,
             1.0f, 0, TT, DD, DD, 1, BB);
    // ck|cv = temporal_out @ Wkv^T + bkv (rows 768..2304), N=1536
    run_gemm(stream, 1, toutb, sTD, 0, DD, c_wqkv + (long long)DD * DD, 0, 0, DD, nullptr, 0,
             qkvb + DD, sT3D, 0, 3 * DD, c_bqkv + DD, 0, nullptr, 0, 0,
             1.0f, 0, TT, 2 * DD, DD, 1, BB);
    // fused attention
    attn_kernel<<<dim3(TT / 64, BB * HH), 256, 0, stream>>>(qkvb, tmp1, 0, qk_scale);
    // x1 = x + (fused_attn @ cross_wo^T + cross_bo)
    run_gemm(stream, 1, tmp1, sTD, 0, DD, c_wo, 0, 0, DD, nullptr, 0,
             x1b, sTD, 0, DD, c_bo, 0, x, sTD, DD,
             1.0f, 0, TT, DD, DD, 1, BB);

    // ---- MLP ----
    ln_kernel<<<4096, 256, 0, stream>>>(x1b, gm, bm, tmp2);
    // y = gelu(ln @ mlp_w1^T + b1)  -> Sb (aliased as y, 4096x3072)
    run_gemm(stream, 1, tmp2, sTD, 0, DD, m_w1, 0, 0, DD, nullptr, 0,
             Sb, (long long)TT * 4 * DD, 0, 4 * DD, m_b1, 0, nullptr, 0, 0,
             1.0f, 1, TT, 4 * DD, DD, 1, BB);
    // out = x1 + y @ mlp_w2^T + b2
    run_gemm(stream, 1, Sb, (long long)TT * 4 * DD, 0, 4 * DD, m_w2, 0, 0, 4 * DD, nullptr, 0,
             out, sTD, 0, DD, m_b2, 0, x1b, sTD, DD,
             1.0f, 0, TT, DD, 4 * DD, 1, BB);
}

// Round 2
// 865.976 us; speedup vs baseline: 1.5429x; 1.2372x over previous
//
#include <hip/hip_runtime.h>
#include <math.h>

// Problem constants
#define BB 8
#define TT 512
#define DD 768
#define HH 8
#define HDIM 96

typedef short s16x8 __attribute__((ext_vector_type(8)));
typedef float f32x4 __attribute__((ext_vector_type(4)));
typedef unsigned short u16;

__device__ inline unsigned short f2bf(float f) {
    union { float f; unsigned u; } v; v.f = f;
    unsigned u = v.u;
    unsigned r = (u + 0x7fffu + ((u >> 16) & 1u)) >> 16;
    return (unsigned short)r;
}

__device__ inline float bf2f(u16 h) {
    union { unsigned u; float f; } v; v.u = ((unsigned)h) << 16; return v.f;
}

__device__ inline float gelu_exact(float x) {
    return 0.5f * x * (1.0f + erff(x * 0.70710678118654752440f));
}

__device__ __forceinline__ void gload16(const void* g, void* l) {
    __builtin_amdgcn_global_load_lds(
        (const __attribute__((address_space(1))) unsigned int*)g,
        (__attribute__((address_space(3))) unsigned int*)l,
        16, 0, 0);
}

// ---------------------------------------------------------------------------
// Weight convert: f32 -> bf16 for all 10 weight tensors in one launch.
// Compile-time prefix table; 8 elems / thread.
// ---------------------------------------------------------------------------
#define CUM1  7077888LL
#define CUM2  9437184LL
#define CUM3  11796480LL
#define CUM4  14155776LL
#define CUM5  16515072LL
#define CUM6  18874368LL
#define CUM7  20643840LL
#define CUM8  21233664LL
#define CUM9  23592960LL
#define CUM10 25952256LL

__global__ __launch_bounds__(256) void cvt_kernel(
    const float* __restrict__ s0, const float* __restrict__ s1,
    const float* __restrict__ s2, const float* __restrict__ s3,
    const float* __restrict__ s4, const float* __restrict__ s5,
    const float* __restrict__ s6, const float* __restrict__ s7,
    const float* __restrict__ s8, const float* __restrict__ s9,
    u16* __restrict__ dpool)
{
    long long g = ((long long)blockIdx.x * 256 + threadIdx.x) * 8;
    if (g >= CUM10) return;
    const float* s; long long base;
    if      (g < CUM1) { s = s0; base = 0; }
    else if (g < CUM2) { s = s1; base = CUM1; }
    else if (g < CUM3) { s = s2; base = CUM2; }
    else if (g < CUM4) { s = s3; base = CUM3; }
    else if (g < CUM5) { s = s4; base = CUM4; }
    else if (g < CUM6) { s = s5; base = CUM5; }
    else if (g < CUM7) { s = s6; base = CUM6; }
    else if (g < CUM8) { s = s7; base = CUM7; }
    else if (g < CUM9) { s = s8; base = CUM8; }
    else               { s = s9; base = CUM9; }
    long long i = g - base;
    float4 a = *(const float4*)(s + i);
    float4 b = *(const float4*)(s + i + 4);
    s16x8 o;
    o[0] = f2bf(a.x); o[1] = f2bf(a.y); o[2] = f2bf(a.z); o[3] = f2bf(a.w);
    o[4] = f2bf(b.x); o[5] = f2bf(b.y); o[6] = f2bf(b.z); o[7] = f2bf(b.w);
    *(s16x8*)(dpool + g) = o;
}

// ---------------------------------------------------------------------------
// bf16 GEMM: C[z] = A[z] * B^T (+bias) (gelu?) (+resid)
//   A bf16 [512,K] per z (stride sAb), B bf16 [N,K] (expert-indexed via bidx).
//   Tile 128x128, BK=32, 4 waves each 64x64 via 4x4 MFMA 16x16x32.
//   Staging via global_load_lds into k-major subtile LDS [kk][128][8]:
//   conflict-free ds_read_b128 frag reads, zero staging VALU.
//   OUT_BF16: C dtype. RES_MODE: 0 none, 1 f32 resid, 2 bf16 resid.
//   Requires M=512, N%128==0, K%32==0.
// ---------------------------------------------------------------------------
template<int OUT_BF16, int RES_MODE>
__global__ __launch_bounds__(256) void gemm_bf16_kernel(
    const u16* __restrict__ A, long long sAb, int lda,
    const u16* __restrict__ B, const int* __restrict__ bidx, long long sBexp, int ldb,
    void* __restrict__ Cv, long long sCb, int ldc,
    const float* __restrict__ bias, long long sBiasExp,
    const void* __restrict__ residv, long long sResB, int ldr,
    int act, int N, int K)
{
    int zb = blockIdx.z;
    const u16* Ab = A + zb * sAb;
    const u16* Bb = B + (bidx ? (long long)bidx[zb] * sBexp : 0);
    const float* biasb = bias ? (bias + (bidx ? (long long)bidx[zb] * sBiasExp : 0)) : nullptr;

    int n0 = blockIdx.x * 128;
    int m0 = blockIdx.y * 128;

    __shared__ __align__(16) u16 As[4 * 128 * 8];  // [kk][row][8]  8 KB
    __shared__ __align__(16) u16 Bs[4 * 128 * 8];

    int tid = threadIdx.x;
    int wave = tid >> 6, lane = tid & 63;
    int wr = wave >> 1, wc = wave & 1;
    int lrow = lane & 15, lkg = lane >> 4;

    f32x4 acc[4][4];
    #pragma unroll
    for (int i = 0; i < 4; i++)
        #pragma unroll
        for (int j = 0; j < 4; j++)
            acc[i][j] = (f32x4){0.f, 0.f, 0.f, 0.f};

    // staging slots: s and s+256; slot s -> LDS bytes [s*16, s*16+16),
    // global src row (s&127), k-window (s>>7)*8
    int s0i = tid, s1i = tid + 256;
    const u16* agp0 = Ab + (long long)(m0 + (s0i & 127)) * lda + (s0i >> 7) * 8;
    const u16* agp1 = Ab + (long long)(m0 + (s1i & 127)) * lda + (s1i >> 7) * 8;
    const u16* bgp0 = Bb + (long long)(n0 + (s0i & 127)) * ldb + (s0i >> 7) * 8;
    const u16* bgp1 = Bb + (long long)(n0 + (s1i & 127)) * ldb + (s1i >> 7) * 8;
    u16* al0 = &As[s0i * 8];
    u16* al1 = &As[s1i * 8];
    u16* bl0 = &Bs[s0i * 8];
    u16* bl1 = &Bs[s1i * 8];

    int nK = K >> 5;
    for (int kt = 0; kt < nK; ++kt) {
        __syncthreads();   // all waves done reading LDS from previous step
        gload16(agp0, al0);
        gload16(agp1, al1);
        gload16(bgp0, bl0);
        gload16(bgp1, bl1);
        agp0 += 32; agp1 += 32; bgp0 += 32; bgp1 += 32;
        __syncthreads();   // drains vmcnt(0): LDS data visible

        s16x8 af[4], bf[4];
        #pragma unroll
        for (int i = 0; i < 4; ++i)
            af[i] = *(const s16x8*)&As[(lkg * 128 + wr * 64 + i * 16 + lrow) * 8];
        #pragma unroll
        for (int j = 0; j < 4; ++j)
            bf[j] = *(const s16x8*)&Bs[(lkg * 128 + wc * 64 + j * 16 + lrow) * 8];
        #pragma unroll
        for (int i = 0; i < 4; ++i)
            #pragma unroll
            for (int j = 0; j < 4; ++j)
                acc[i][j] = __builtin_amdgcn_mfma_f32_16x16x32_bf16(af[i], bf[j], acc[i][j], 0, 0, 0);
    }

    // epilogue: C/D layout col=lane&15, row=(lane>>4)*4+reg
    float* Cf = (float*)Cv + zb * sCb;
    u16* Ch = (u16*)Cv + zb * sCb;
    const float* Rf = (const float*)residv + zb * sResB;
    const u16* Rh = (const u16*)residv + zb * sResB;
    int col16 = lane & 15;
    int rq = (lane >> 4) * 4;
    #pragma unroll
    for (int j = 0; j < 4; ++j) {
        int n = n0 + wc * 64 + j * 16 + col16;
        float bv = biasb ? biasb[n] : 0.0f;
        #pragma unroll
        for (int i = 0; i < 4; ++i) {
            #pragma unroll
            for (int r = 0; r < 4; ++r) {
                int m = m0 + wr * 64 + i * 16 + rq + r;
                float v = acc[i][j][r] + bv;
                if (act == 1) v = gelu_exact(v);
                if (RES_MODE == 1) v += Rf[(long long)m * ldr + n];
                if (RES_MODE == 2) v += bf2f(Rh[(long long)m * ldr + n]);
                if (OUT_BF16) Ch[(long long)m * ldc + n] = f2bf(v);
                else          Cf[(long long)m * ldc + n] = v;
            }
        }
    }
}

// ---------------------------------------------------------------------------
// Fused flash attention (bf16 I/O): O = softmax(scale * Q K^T [causal]) V.
// QKV bf16 packed [B][T][3*D]; Out bf16 [B][T][D].
// Grid (T/64, B*H), 256 threads = 4 waves, each wave owns 16 query rows.
// ---------------------------------------------------------------------------
__global__ __launch_bounds__(256, 2) void attn_kernel(
    const u16* __restrict__ QKV, u16* __restrict__ Out,
    int causal, float scale)
{
    int qt = blockIdx.x;
    int bh = blockIdx.y;
    int b = bh >> 3;
    int h = bh & 7;
    const u16* Qb = QKV + (long long)b * TT * 3 * DD + (long long)h * HDIM;
    const u16* Kb = Qb + DD;
    const u16* Vb = Qb + 2 * DD;
    u16* Ob = Out + (long long)b * TT * DD + (long long)h * HDIM;

    __shared__ __align__(16) u16 Qs[64 * 104];  // [qrow][d], stride 104
    __shared__ __align__(16) u16 Ks[64 * 104];
    __shared__ __align__(16) u16 Vs[96 * 72];   // [d][krow], stride 72
    __shared__ __align__(16) u16 Ps[64 * 72];   // [qrow][krow]

    int tid = threadIdx.x;
    int wave = tid >> 6;
    int lane = tid & 63;
    int col16 = lane & 15;
    int lkg = lane >> 4;
    int lk = lkg * 8;
    int m0 = qt * 64;

    // ---- stage Q tile 64x96 bf16 (768 x 8-elem slots, 3/thread) ----
    #pragma unroll
    for (int it = 0; it < 3; ++it) {
        int s = tid + it * 256;
        int r = s / 12, c8 = (s % 12) * 8;
        *(s16x8*)&Qs[r * 104 + c8] = *(const s16x8*)(Qb + (long long)(m0 + r) * (3 * DD) + c8);
    }
    __syncthreads();

    s16x8 qf[3];
    #pragma unroll
    for (int kk = 0; kk < 3; ++kk)
        qf[kk] = *(const s16x8*)&Qs[(wave * 16 + col16) * 104 + kk * 32 + lk];

    // ---- QK^T ----
    f32x4 acc[32];
    #pragma unroll
    for (int n = 0; n < 32; ++n) acc[n] = (f32x4){0.f, 0.f, 0.f, 0.f};

    #pragma unroll
    for (int kt = 0; kt < 8; ++kt) {
        #pragma unroll
        for (int it = 0; it < 3; ++it) {
            int s = tid + it * 256;
            int r = s / 12, c8 = (s % 12) * 8;
            *(s16x8*)&Ks[r * 104 + c8] = *(const s16x8*)(Kb + (long long)(kt * 64 + r) * (3 * DD) + c8);
        }
        __syncthreads();
        #pragma unroll
        for (int kk = 0; kk < 3; ++kk) {
            #pragma unroll
            for (int j = 0; j < 4; ++j) {
                s16x8 bfr = *(const s16x8*)&Ks[(j * 16 + col16) * 104 + kk * 32 + lk];
                acc[kt * 4 + j] = __builtin_amdgcn_mfma_f32_16x16x32_bf16(qf[kk], bfr, acc[kt * 4 + j], 0, 0, 0);
            }
        }
        __syncthreads();
    }

    // ---- softmax (registers + shfl only) ----
    int rowbase = m0 + wave * 16 + lkg * 4;
    float mx[4];
    #pragma unroll
    for (int r = 0; r < 4; ++r) mx[r] = -3.0e38f;
    #pragma unroll
    for (int n = 0; n < 32; ++n) {
        int colg = n * 16 + col16;
        #pragma unroll
        for (int r = 0; r < 4; ++r) {
            float v = acc[n][r] * scale;
            if (causal && colg > rowbase + r) v = -3.0e38f;
            acc[n][r] = v;
            mx[r] = fmaxf(mx[r], v);
        }
    }
    #pragma unroll
    for (int m = 1; m <= 8; m <<= 1)
        #pragma unroll
        for (int r = 0; r < 4; ++r)
            mx[r] = fmaxf(mx[r], __shfl_xor(mx[r], m, 64));

    float sum[4] = {0.f, 0.f, 0.f, 0.f};
    #pragma unroll
    for (int n = 0; n < 32; ++n) {
        #pragma unroll
        for (int r = 0; r < 4; ++r) {
            float e = __expf(acc[n][r] - mx[r]);
            acc[n][r] = e;
            sum[r] += e;
        }
    }
    #pragma unroll
    for (int m = 1; m <= 8; m <<= 1)
        #pragma unroll
        for (int r = 0; r < 4; ++r)
            sum[r] += __shfl_xor(sum[r], m, 64);
    float inv[4];
    #pragma unroll
    for (int r = 0; r < 4; ++r) inv[r] = 1.0f / sum[r];

    // ---- PV ----
    f32x4 oacc[6];
    #pragma unroll
    for (int j = 0; j < 6; ++j) oacc[j] = (f32x4){0.f, 0.f, 0.f, 0.f};

    #pragma unroll
    for (int kt = 0; kt < 8; ++kt) {
        __syncthreads();
        // write P strip (unnormalized e, bf16)
        #pragma unroll
        for (int j = 0; j < 4; ++j) {
            #pragma unroll
            for (int r = 0; r < 4; ++r)
                Ps[(wave * 16 + lkg * 4 + r) * 72 + j * 16 + col16] = f2bf(acc[kt * 4 + j][r]);
        }
        // stage V tile transposed: V[kt*64+key][d] -> Vs[d][key]
        #pragma unroll
        for (int it = 0; it < 3; ++it) {
            int s = tid + it * 256;
            int key = s / 12, c8 = (s % 12) * 8;
            s16x8 v = *(const s16x8*)(Vb + (long long)(kt * 64 + key) * (3 * DD) + c8);
            #pragma unroll
            for (int e = 0; e < 8; ++e)
                Vs[(c8 + e) * 72 + key] = (u16)v[e];
        }
        __syncthreads();
        #pragma unroll
        for (int kk = 0; kk < 2; ++kk) {
            s16x8 pf = *(const s16x8*)&Ps[(wave * 16 + col16) * 72 + kk * 32 + lk];
            #pragma unroll
            for (int j = 0; j < 6; ++j) {
                s16x8 vf = *(const s16x8*)&Vs[(j * 16 + col16) * 72 + kk * 32 + lk];
                oacc[j] = __builtin_amdgcn_mfma_f32_16x16x32_bf16(pf, vf, oacc[j], 0, 0, 0);
            }
        }
    }

    // ---- epilogue ----
    int rquad = lkg * 4;
    #pragma unroll
    for (int j = 0; j < 6; ++j) {
        int d = j * 16 + col16;
        #pragma unroll
        for (int r = 0; r < 4; ++r) {
            int row = m0 + wave * 16 + rquad + r;
            Ob[(long long)row * DD + d] = f2bf(oacc[j][r] * inv[r]);
        }
    }
}

// ---------------------------------------------------------------------------
// LayerNorm over last dim (768), bf16 output. One block per row.
// ---------------------------------------------------------------------------
__global__ __launch_bounds__(256) void ln_kernel(
    const float* __restrict__ x, const float* __restrict__ g,
    const float* __restrict__ b, u16* __restrict__ out)
{
    long long row = blockIdx.x;
    const float* xr = x + row * DD;
    u16* orow = out + row * DD;
    int t = threadIdx.x;
    float vals[3];
    float s = 0.f, ss = 0.f;
    #pragma unroll
    for (int i = 0; i < 3; i++) {
        float v = xr[t + i * 256];
        vals[i] = v; s += v; ss += v * v;
    }
    __shared__ float rs[256], rss[256];
    rs[t] = s; rss[t] = ss; __syncthreads();
    for (int k = 128; k > 0; k >>= 1) {
        if (t < k) { rs[t] += rs[t + k]; rss[t] += rss[t + k]; }
        __syncthreads();
    }
    float mean = rs[0] * (1.0f / DD);
    float var = rss[0] * (1.0f / DD) - mean * mean;
    float inv = rsqrtf(var + 1e-5f);
    #pragma unroll
    for (int i = 0; i < 3; i++) {
        int d = t + i * 256;
        orow[d] = f2bf((vals[i] - mean) * inv * g[d] + b[d]);
    }
}

// ---------------------------------------------------------------------------
// Router part 1: partial column sums of x over T.
// ---------------------------------------------------------------------------
__global__ __launch_bounds__(256) void mean_part_kernel(
    const float* __restrict__ x, float* __restrict__ part)
{
    int b = blockIdx.x, dseg = blockIdx.y, rc = blockIdx.z;
    int d = dseg * 256 + threadIdx.x;
    const float* xb = x + (long long)b * TT * DD;
    float s = 0.f;
    int r0 = rc * 64;
    for (int r = r0; r < r0 + 64; ++r) s += xb[(long long)r * DD + d];
    part[((long long)b * 8 + rc) * DD + d] = s;
}

// ---------------------------------------------------------------------------
// Router part 2.
// ---------------------------------------------------------------------------
__global__ __launch_bounds__(128) void router_kernel(
    const float* __restrict__ part, const float* __restrict__ w1,
    const float* __restrict__ b1, const float* __restrict__ w2,
    const float* __restrict__ b2, int* __restrict__ idx)
{
    int b = blockIdx.x, t = threadIdx.x;
    __shared__ float xm[DD];
    __shared__ float h[128];
    __shared__ float logits[8];
    for (int i = t; i < DD; i += 128) {
        float s = 0.f;
        for (int rc = 0; rc < 8; ++rc) s += part[((long long)b * 8 + rc) * DD + i];
        xm[i] = s * (1.0f / TT);
    }
    __syncthreads();
    {
        float s = b1[t];
        const float* w = w1 + (long long)t * DD;
        for (int d = 0; d < DD; ++d) s += xm[d] * w[d];
        h[t] = gelu_exact(s);
    }
    __syncthreads();
    if (t < 8) {
        float s = b2[t];
        const float* w = w2 + t * 128;
        for (int d = 0; d < 128; ++d) s += h[d] * w[d];
        logits[t] = s;
    }
    __syncthreads();
    if (t == 0) {
        int bsix = 0;
        for (int i = 1; i < 4; i++) if (logits[i] > logits[bsix]) bsix = i;
        int btix = 4;
        for (int i = 5; i < 8; i++) if (logits[i] > logits[btix]) btix = i;
        idx[b] = bsix;
        idx[b + BB] = btix - 4;
    }
}

// ---------------------------------------------------------------------------
static void run_gemm2(hipStream_t stream,
    const u16* A, long long sAb, int lda,
    const u16* B, const int* bidx, long long sBexp, int ldb,
    void* C, long long sCb, int ldc,
    const float* bias, long long sBiasExp,
    const void* resid, long long sResB, int ldr,
    int act, int N, int K, int outbf, int resmode)
{
    dim3 grid(N / 128, 4, BB);
    if (outbf && resmode == 0)
        gemm_bf16_kernel<1, 0><<<grid, 256, 0, stream>>>(A, sAb, lda, B, bidx, sBexp, ldb,
            C, sCb, ldc, bias, sBiasExp, resid, sResB, ldr, act, N, K);
    else if (outbf)
        gemm_bf16_kernel<1, 2><<<grid, 256, 0, stream>>>(A, sAb, lda, B, bidx, sBexp, ldb,
            C, sCb, ldc, bias, sBiasExp, resid, sResB, ldr, act, N, K);
    else
        gemm_bf16_kernel<0, 1><<<grid, 256, 0, stream>>>(A, sAb, lda, B, bidx, sBexp, ldb,
            C, sCb, ldc, bias, sBiasExp, resid, sResB, ldr, act, N, K);
}

extern "C" void kernel_launch(void* const* d_in, const int* in_sizes, int n_in,
                              void* d_out, int out_size, void* d_ws, size_t ws_size,
                              hipStream_t stream)
{
    const float* x       = (const float*)d_in[0];
    const float* rw1     = (const float*)d_in[1];
    const float* rb1     = (const float*)d_in[2];
    const float* rw2     = (const float*)d_in[3];
    const float* rb2     = (const float*)d_in[4];
    const float* gs      = (const float*)d_in[5];
    const float* bs      = (const float*)d_in[6];
    const float* gt      = (const float*)d_in[7];
    const float* btt     = (const float*)d_in[8];
    const float* gm      = (const float*)d_in[9];
    const float* bm      = (const float*)d_in[10];
    const float* sp_wqkv = (const float*)d_in[11];
    const float* sp_bqkv = (const float*)d_in[12];
    const float* sp_wo   = (const float*)d_in[13];
    const float* sp_bo   = (const float*)d_in[14];
    const float* tp_wq   = (const float*)d_in[15];
    const float* tp_bq   = (const float*)d_in[16];
    const float* tp_wk   = (const float*)d_in[17];
    const float* tp_bk   = (const float*)d_in[18];
    const float* tp_wv   = (const float*)d_in[19];
    const float* tp_bv   = (const float*)d_in[20];
    const float* tp_wo   = (const float*)d_in[21];
    const float* tp_bo   = (const float*)d_in[22];
    const float* c_wqkv  = (const float*)d_in[23];
    const float* c_bqkv  = (const float*)d_in[24];
    const float* c_wo    = (const float*)d_in[25];
    const float* c_bo    = (const float*)d_in[26];
    const float* m_w1    = (const float*)d_in[27];
    const float* m_b1    = (const float*)d_in[28];
    const float* m_w2    = (const float*)d_in[29];
    const float* m_b2    = (const float*)d_in[30];
    float* out = (float*)d_out;

    float* ws = (float*)d_ws;
    size_t o = 0;
    float* part  = ws + o; o += (size_t)BB * 8 * DD;
    int*   idx   = (int*)(ws + o); o += 16;
    float* x1b   = ws + o; o += (size_t)4096 * DD;            // f32 (x + fused)
    u16* xnb   = (u16*)(ws + o); o += (size_t)4096 * DD / 2;  // LN out (bf16)
    u16* tmp1b = (u16*)(ws + o); o += (size_t)4096 * DD / 2;  // attention out
    u16* tmp2b = (u16*)(ws + o); o += (size_t)4096 * DD / 2;  // LN for mlp
    u16* soutb = (u16*)(ws + o); o += (size_t)4096 * DD / 2;  // spatial_out
    u16* toutb = (u16*)(ws + o); o += (size_t)4096 * DD / 2;  // temporal_out
    u16* qkvb  = (u16*)(ws + o); o += (size_t)4096 * 2304 / 2;// q|k|v packed bf16
    u16* yb    = (u16*)(ws + o); o += (size_t)4096 * 3072 / 2;// mlp hidden bf16
    u16* wpool = (u16*)(ws + o); o += (size_t)CUM10 / 2;      // bf16 weights

    u16* w_sp_qkv = wpool;
    u16* w_sp_wo  = wpool + CUM1;
    u16* w_tp_q   = wpool + CUM2;
    u16* w_tp_k   = wpool + CUM3;
    u16* w_tp_v   = wpool + CUM4;
    u16* w_tp_o   = wpool + CUM5;
    u16* w_c_qkv  = wpool + CUM6;
    u16* w_c_wo   = wpool + CUM7;
    u16* w_m1     = wpool + CUM8;
    u16* w_m2     = wpool + CUM9;

    int* idx_s = idx;
    int* idx_t = idx + BB;

    const long long sTD  = (long long)TT * DD;       // 512*768
    const long long sT3D = (long long)TT * 3 * DD;   // 512*2304
    const long long sT4D = (long long)TT * 4 * DD;   // 512*3072
    const float qk_scale = 1.0f / sqrtf((float)HDIM);

    // ---- weight convert (f32 -> bf16) ----
    cvt_kernel<<<(int)((CUM10 / 8 + 255) / 256), 256, 0, stream>>>(
        sp_wqkv, sp_wo, tp_wq, tp_wk, tp_wv, tp_wo, c_wqkv, c_wo, m_w1, m_w2, wpool);

    // ---- router ----
    mean_part_kernel<<<dim3(BB, 3, 8), 256, 0, stream>>>(x, part);
    router_kernel<<<BB, 128, 0, stream>>>(part, rw1, rb1, rw2, rb2, idx);

    // ---- spatial branch ----
    ln_kernel<<<4096, 256, 0, stream>>>(x, gs, bs, xnb);
    // qkv = xn @ sp_wqkv[idx_s]^T + sp_bqkv[idx_s]
    run_gemm2(stream, xnb, sTD, DD, w_sp_qkv, idx_s, (long long)3 * DD * DD, DD,
              qkvb, sT3D, 3 * DD, sp_bqkv, 3 * DD, nullptr, 0, 0,
              0, 3 * DD, DD, 1, 0);
    attn_kernel<<<dim3(TT / 64, BB * HH), 256, 0, stream>>>(qkvb, tmp1b, 0, qk_scale);
    // spatial_out = O @ sp_wo[idx_s]^T + sp_bo[idx_s]
    run_gemm2(stream, tmp1b, sTD, DD, w_sp_wo, idx_s, (long long)DD * DD, DD,
              soutb, sTD, DD, sp_bo, DD, nullptr, 0, 0,
              0, DD, DD, 1, 0);

    // ---- temporal branch ----
    ln_kernel<<<4096, 256, 0, stream>>>(x, gt, btt, xnb);
    run_gemm2(stream, xnb, sTD, DD, w_tp_q, idx_t, (long long)DD * DD, DD,
              qkvb, sT3D, 3 * DD, tp_bq, DD, nullptr, 0, 0,
              0, DD, DD, 1, 0);
    run_gemm2(stream, xnb, sTD, DD, w_tp_k, idx_t, (long long)DD * DD, DD,
              qkvb + DD, sT3D, 3 * DD, tp_bk, DD, nullptr, 0, 0,
              0, DD, DD, 1, 0);
    run_gemm2(stream, xnb, sTD, DD, w_tp_v, idx_t, (long long)DD * DD, DD,
              qkvb + 2 * DD, sT3D, 3 * DD, tp_bv, DD, nullptr, 0, 0,
              0, DD, DD, 1, 0);
    attn_kernel<<<dim3(TT / 64, BB * HH), 256, 0, stream>>>(qkvb, tmp1b, 1, qk_scale);
    // temporal_out = xt + O @ tp_wo[idx_t]^T + tp_bo[idx_t]   (bf16 resid xnb)
    run_gemm2(stream, tmp1b, sTD, DD, w_tp_o, idx_t, (long long)DD * DD, DD,
              toutb, sTD, DD, tp_bo, DD, xnb, sTD, DD,
              0, DD, DD, 1, 2);

    // ---- cross attention ----
    run_gemm2(stream, soutb, sTD, DD, w_c_qkv, nullptr, 0, DD,
              qkvb, sT3D, 3 * DD, c_bqkv, 0, nullptr, 0, 0,
              0, DD, DD, 1, 0);
    run_gemm2(stream, toutb, sTD, DD, w_c_qkv + (long long)DD * DD, nullptr, 0, DD,
              qkvb + DD, sT3D, 3 * DD, c_bqkv + DD, 0, nullptr, 0, 0,
              0, 2 * DD, DD, 1, 0);
    attn_kernel<<<dim3(TT / 64, BB * HH), 256, 0, stream>>>(qkvb, tmp1b, 0, qk_scale);
    // x1 = x + (fused_attn @ cross_wo^T + cross_bo)   (f32 out, f32 resid)
    run_gemm2(stream, tmp1b, sTD, DD, w_c_wo, nullptr, 0, DD,
              x1b, sTD, DD, c_bo, 0, x, sTD, DD,
              0, DD, DD, 0, 1);

    // ---- MLP ----
    ln_kernel<<<4096, 256, 0, stream>>>(x1b, gm, bm, tmp2b);
    // y = gelu(ln @ mlp_w1^T + b1) -> bf16
    run_gemm2(stream, tmp2b, sTD, DD, w_m1, nullptr, 0, DD,
              yb, sT4D, 4 * DD, m_b1, 0, nullptr, 0, 0,
              1, 4 * DD, DD, 1, 0);
    // out = x1 + y @ mlp_w2^T + b2   (f32 out, f32 resid)
    run_gemm2(stream, yb, sT4D, 4 * DD, w_m2, nullptr, 0, 4 * DD,
              out, sTD, DD, m_b2, 0, x1b, sTD, DD,
              0, DD, 4 * DD, 0, 1);
}

// Round 3
// 832.587 us; speedup vs baseline: 1.6047x; 1.0401x over previous
//
#include <hip/hip_runtime.h>
#include <math.h>

// Problem constants
#define BB 8
#define TT 512
#define DD 768
#define HH 8
#define HDIM 96
#define DDDD 589824LL   // 768*768

typedef short s16x8 __attribute__((ext_vector_type(8)));
typedef float f32x4 __attribute__((ext_vector_type(4)));
typedef unsigned short u16;

__device__ inline unsigned short f2bf(float f) {
    union { float f; unsigned u; } v; v.f = f;
    unsigned u = v.u;
    unsigned r = (u + 0x7fffu + ((u >> 16) & 1u)) >> 16;
    return (unsigned short)r;
}

__device__ inline float bf2f(u16 h) {
    union { unsigned u; float f; } v; v.u = ((unsigned)h) << 16; return v.f;
}

__device__ inline float gelu_exact(float x) {
    return 0.5f * x * (1.0f + erff(x * 0.70710678118654752440f));
}

__device__ __forceinline__ void gload16(const void* g, void* l) {
    __builtin_amdgcn_global_load_lds(
        (const __attribute__((address_space(1))) unsigned int*)g,
        (__attribute__((address_space(3))) unsigned int*)l,
        16, 0, 0);
}

// ---------------------------------------------------------------------------
// Weight convert: f32 -> bf16 for all 10 weight tensors in one launch.
// tp_wq/wk/wv (tensors 2,3,4) are written INTERLEAVED per expert:
//   dest[CUM2 + e*3*DDDD + {0,1,2}*DDDD + r]  so temporal qkv is one GEMM.
// ---------------------------------------------------------------------------
#define CUM1  7077888LL
#define CUM2  9437184LL
#define CUM3  11796480LL
#define CUM4  14155776LL
#define CUM5  16515072LL
#define CUM6  18874368LL
#define CUM7  20643840LL
#define CUM8  21233664LL
#define CUM9  23592960LL
#define CUM10 25952256LL

__global__ __launch_bounds__(256) void cvt_kernel(
    const float* __restrict__ s0, const float* __restrict__ s1,
    const float* __restrict__ s2, const float* __restrict__ s3,
    const float* __restrict__ s4, const float* __restrict__ s5,
    const float* __restrict__ s6, const float* __restrict__ s7,
    const float* __restrict__ s8, const float* __restrict__ s9,
    u16* __restrict__ dpool)
{
    long long g = ((long long)blockIdx.x * 256 + threadIdx.x) * 8;
    if (g >= CUM10) return;
    const float* s; long long base;
    int tp = -1;
    if      (g < CUM1) { s = s0; base = 0; }
    else if (g < CUM2) { s = s1; base = CUM1; }
    else if (g < CUM3) { s = s2; base = CUM2; tp = 0; }
    else if (g < CUM4) { s = s3; base = CUM3; tp = 1; }
    else if (g < CUM5) { s = s4; base = CUM4; tp = 2; }
    else if (g < CUM6) { s = s5; base = CUM5; }
    else if (g < CUM7) { s = s6; base = CUM6; }
    else if (g < CUM8) { s = s7; base = CUM7; }
    else if (g < CUM9) { s = s8; base = CUM8; }
    else               { s = s9; base = CUM9; }
    long long i = g - base;
    long long d = g;
    if (tp >= 0) {
        long long e = i / DDDD, r = i - e * DDDD;
        d = CUM2 + e * 3 * DDDD + (long long)tp * DDDD + r;
    }
    float4 a = *(const float4*)(s + i);
    float4 b = *(const float4*)(s + i + 4);
    s16x8 o;
    o[0] = f2bf(a.x); o[1] = f2bf(a.y); o[2] = f2bf(a.z); o[3] = f2bf(a.w);
    o[4] = f2bf(b.x); o[5] = f2bf(b.y); o[6] = f2bf(b.z); o[7] = f2bf(b.w);
    *(s16x8*)(dpool + d) = o;
}

// pack temporal biases [4][2304] = bq|bk|bv
__global__ __launch_bounds__(256) void pack_tpb_kernel(
    const float* __restrict__ bq, const float* __restrict__ bk,
    const float* __restrict__ bv, float* __restrict__ dst)
{
    int t = blockIdx.x * 256 + threadIdx.x;
    if (t >= 4 * 2304) return;
    int e = t / 2304, n = t - e * 2304;
    float v = (n < 768) ? bq[e * 768 + n]
            : (n < 1536) ? bk[e * 768 + n - 768]
            : bv[e * 768 + n - 1536];
    dst[t] = v;
}

// ---------------------------------------------------------------------------
// bf16 GEMM: C[z] = A[z] * B^T (+bias) (gelu?) (+resid)
//   Tile 128x128, BK=128, 4 waves each 64x64 via 4x4 MFMA 16x16x32.
//   LDS [kwin][128][8] (16 kwin of 8 shorts), 32 KB per matrix, single-buffer.
//   Staging: 16 global_load_lds(16B)/thread per K-step -> one vmcnt drain
//   per 128-K slab (amortizes latency 4x vs BK=32).
//   OUT_BF16: C dtype. RES_MODE: 0 none, 1 f32 resid, 2 bf16 resid.
//   Requires M=512, N%128==0, K%128==0.
// ---------------------------------------------------------------------------
template<int OUT_BF16, int RES_MODE>
__global__ __launch_bounds__(256) void gemm_bf16_kernel(
    const u16* __restrict__ A, long long sAb, int lda,
    const u16* __restrict__ B, const int* __restrict__ bidx, long long sBexp, int ldb,
    void* __restrict__ Cv, long long sCb, int ldc,
    const float* __restrict__ bias, long long sBiasExp,
    const void* __restrict__ residv, long long sResB, int ldr,
    int act, int N, int K)
{
    int zb = blockIdx.z;
    const u16* Ab = A + zb * sAb;
    const u16* Bb = B + (bidx ? (long long)bidx[zb] * sBexp : 0);
    const float* biasb = bias ? (bias + (bidx ? (long long)bidx[zb] * sBiasExp : 0)) : nullptr;

    int n0 = blockIdx.x * 128;
    int m0 = blockIdx.y * 128;

    __shared__ __align__(16) u16 As[16 * 128 * 8];  // 32 KB
    __shared__ __align__(16) u16 Bs[16 * 128 * 8];  // 32 KB

    int tid = threadIdx.x;
    int wave = tid >> 6, lane = tid & 63;
    int wr = wave >> 1, wc = wave & 1;
    int lrow = lane & 15, lkg = lane >> 4;

    f32x4 acc[4][4];
    #pragma unroll
    for (int i = 0; i < 4; i++)
        #pragma unroll
        for (int j = 0; j < 4; j++)
            acc[i][j] = (f32x4){0.f, 0.f, 0.f, 0.f};

    // staging: row = tid&127 (constant per thread), kw0 = tid>>7 (0/1);
    // iteration it covers kwin = kw0 + 2*it  (all 16 windows)
    int row = tid & 127, kw0 = tid >> 7;
    const u16* ag = Ab + (long long)(m0 + row) * lda + kw0 * 8;
    const u16* bg = Bb + (long long)(n0 + row) * ldb + kw0 * 8;
    u16* asl = &As[(kw0 * 128 + row) * 8];
    u16* bsl = &Bs[(kw0 * 128 + row) * 8];

    int nK = K >> 7;
    for (int kt = 0; kt < nK; ++kt) {
        __syncthreads();   // all waves done reading LDS from previous slab
        #pragma unroll
        for (int it = 0; it < 8; ++it) {
            gload16(ag + it * 16, asl + it * 2048);
            gload16(bg + it * 16, bsl + it * 2048);
        }
        ag += 128; bg += 128;
        __syncthreads();   // drains vmcnt(0): LDS data visible

        #pragma unroll
        for (int kk = 0; kk < 4; ++kk) {
            s16x8 af[4], bf[4];
            #pragma unroll
            for (int i = 0; i < 4; ++i)
                af[i] = *(const s16x8*)&As[((kk * 4 + lkg) * 128 + wr * 64 + i * 16 + lrow) * 8];
            #pragma unroll
            for (int j = 0; j < 4; ++j)
                bf[j] = *(const s16x8*)&Bs[((kk * 4 + lkg) * 128 + wc * 64 + j * 16 + lrow) * 8];
            #pragma unroll
            for (int i = 0; i < 4; ++i)
                #pragma unroll
                for (int j = 0; j < 4; ++j)
                    acc[i][j] = __builtin_amdgcn_mfma_f32_16x16x32_bf16(af[i], bf[j], acc[i][j], 0, 0, 0);
        }
    }

    // epilogue: C/D layout col=lane&15, row=(lane>>4)*4+reg
    float* Cf = (float*)Cv + zb * sCb;
    u16* Ch = (u16*)Cv + zb * sCb;
    const float* Rf = (const float*)residv + zb * sResB;
    const u16* Rh = (const u16*)residv + zb * sResB;
    int col16 = lane & 15;
    int rq = (lane >> 4) * 4;
    #pragma unroll
    for (int j = 0; j < 4; ++j) {
        int n = n0 + wc * 64 + j * 16 + col16;
        float bv = biasb ? biasb[n] : 0.0f;
        #pragma unroll
        for (int i = 0; i < 4; ++i) {
            #pragma unroll
            for (int r = 0; r < 4; ++r) {
                int m = m0 + wr * 64 + i * 16 + rq + r;
                float v = acc[i][j][r] + bv;
                if (act == 1) v = gelu_exact(v);
                if (RES_MODE == 1) v += Rf[(long long)m * ldr + n];
                if (RES_MODE == 2) v += bf2f(Rh[(long long)m * ldr + n]);
                if (OUT_BF16) Ch[(long long)m * ldc + n] = f2bf(v);
                else          Cf[(long long)m * ldc + n] = v;
            }
        }
    }
}

// ---------------------------------------------------------------------------
// Fused flash attention (bf16 I/O): O = softmax(scale * Q K^T [causal]) V.
// QKV bf16 packed [B][T][3*D]; Out bf16 [B][T][D].
// Grid (T/64, B*H), 256 threads = 4 waves, each wave owns 16 query rows.
// ---------------------------------------------------------------------------
__global__ __launch_bounds__(256, 2) void attn_kernel(
    const u16* __restrict__ QKV, u16* __restrict__ Out,
    int causal, float scale)
{
    int qt = blockIdx.x;
    int bh = blockIdx.y;
    int b = bh >> 3;
    int h = bh & 7;
    const u16* Qb = QKV + (long long)b * TT * 3 * DD + (long long)h * HDIM;
    const u16* Kb = Qb + DD;
    const u16* Vb = Qb + 2 * DD;
    u16* Ob = Out + (long long)b * TT * DD + (long long)h * HDIM;

    __shared__ __align__(16) u16 Qs[64 * 104];  // [qrow][d], stride 104
    __shared__ __align__(16) u16 Ks[64 * 104];
    __shared__ __align__(16) u16 Vs[96 * 72];   // [d][krow], stride 72
    __shared__ __align__(16) u16 Ps[64 * 72];   // [qrow][krow]

    int tid = threadIdx.x;
    int wave = tid >> 6;
    int lane = tid & 63;
    int col16 = lane & 15;
    int lkg = lane >> 4;
    int lk = lkg * 8;
    int m0 = qt * 64;

    // ---- stage Q tile 64x96 bf16 (768 x 8-elem slots, 3/thread) ----
    #pragma unroll
    for (int it = 0; it < 3; ++it) {
        int s = tid + it * 256;
        int r = s / 12, c8 = (s % 12) * 8;
        *(s16x8*)&Qs[r * 104 + c8] = *(const s16x8*)(Qb + (long long)(m0 + r) * (3 * DD) + c8);
    }
    __syncthreads();

    s16x8 qf[3];
    #pragma unroll
    for (int kk = 0; kk < 3; ++kk)
        qf[kk] = *(const s16x8*)&Qs[(wave * 16 + col16) * 104 + kk * 32 + lk];

    // ---- QK^T ----
    f32x4 acc[32];
    #pragma unroll
    for (int n = 0; n < 32; ++n) acc[n] = (f32x4){0.f, 0.f, 0.f, 0.f};

    #pragma unroll
    for (int kt = 0; kt < 8; ++kt) {
        #pragma unroll
        for (int it = 0; it < 3; ++it) {
            int s = tid + it * 256;
            int r = s / 12, c8 = (s % 12) * 8;
            *(s16x8*)&Ks[r * 104 + c8] = *(const s16x8*)(Kb + (long long)(kt * 64 + r) * (3 * DD) + c8);
        }
        __syncthreads();
        #pragma unroll
        for (int kk = 0; kk < 3; ++kk) {
            #pragma unroll
            for (int j = 0; j < 4; ++j) {
                s16x8 bfr = *(const s16x8*)&Ks[(j * 16 + col16) * 104 + kk * 32 + lk];
                acc[kt * 4 + j] = __builtin_amdgcn_mfma_f32_16x16x32_bf16(qf[kk], bfr, acc[kt * 4 + j], 0, 0, 0);
            }
        }
        __syncthreads();
    }

    // ---- softmax (registers + shfl only) ----
    int rowbase = m0 + wave * 16 + lkg * 4;
    float mx[4];
    #pragma unroll
    for (int r = 0; r < 4; ++r) mx[r] = -3.0e38f;
    #pragma unroll
    for (int n = 0; n < 32; ++n) {
        int colg = n * 16 + col16;
        #pragma unroll
        for (int r = 0; r < 4; ++r) {
            float v = acc[n][r] * scale;
            if (causal && colg > rowbase + r) v = -3.0e38f;
            acc[n][r] = v;
            mx[r] = fmaxf(mx[r], v);
        }
    }
    #pragma unroll
    for (int m = 1; m <= 8; m <<= 1)
        #pragma unroll
        for (int r = 0; r < 4; ++r)
            mx[r] = fmaxf(mx[r], __shfl_xor(mx[r], m, 64));

    float sum[4] = {0.f, 0.f, 0.f, 0.f};
    #pragma unroll
    for (int n = 0; n < 32; ++n) {
        #pragma unroll
        for (int r = 0; r < 4; ++r) {
            float e = __expf(acc[n][r] - mx[r]);
            acc[n][r] = e;
            sum[r] += e;
        }
    }
    #pragma unroll
    for (int m = 1; m <= 8; m <<= 1)
        #pragma unroll
        for (int r = 0; r < 4; ++r)
            sum[r] += __shfl_xor(sum[r], m, 64);
    float inv[4];
    #pragma unroll
    for (int r = 0; r < 4; ++r) inv[r] = 1.0f / sum[r];

    // ---- PV ----
    f32x4 oacc[6];
    #pragma unroll
    for (int j = 0; j < 6; ++j) oacc[j] = (f32x4){0.f, 0.f, 0.f, 0.f};

    #pragma unroll
    for (int kt = 0; kt < 8; ++kt) {
        __syncthreads();
        // write P strip (unnormalized e, bf16)
        #pragma unroll
        for (int j = 0; j < 4; ++j) {
            #pragma unroll
            for (int r = 0; r < 4; ++r)
                Ps[(wave * 16 + lkg * 4 + r) * 72 + j * 16 + col16] = f2bf(acc[kt * 4 + j][r]);
        }
        // stage V tile transposed: V[kt*64+key][d] -> Vs[d][key]
        #pragma unroll
        for (int it = 0; it < 3; ++it) {
            int s = tid + it * 256;
            int key = s / 12, c8 = (s % 12) * 8;
            s16x8 v = *(const s16x8*)(Vb + (long long)(kt * 64 + key) * (3 * DD) + c8);
            #pragma unroll
            for (int e = 0; e < 8; ++e)
                Vs[(c8 + e) * 72 + key] = (u16)v[e];
        }
        __syncthreads();
        #pragma unroll
        for (int kk = 0; kk < 2; ++kk) {
            s16x8 pf = *(const s16x8*)&Ps[(wave * 16 + col16) * 72 + kk * 32 + lk];
            #pragma unroll
            for (int j = 0; j < 6; ++j) {
                s16x8 vf = *(const s16x8*)&Vs[(j * 16 + col16) * 72 + kk * 32 + lk];
                oacc[j] = __builtin_amdgcn_mfma_f32_16x16x32_bf16(pf, vf, oacc[j], 0, 0, 0);
            }
        }
    }

    // ---- epilogue ----
    int rquad = lkg * 4;
    #pragma unroll
    for (int j = 0; j < 6; ++j) {
        int d = j * 16 + col16;
        #pragma unroll
        for (int r = 0; r < 4; ++r) {
            int row = m0 + wave * 16 + rquad + r;
            Ob[(long long)row * DD + d] = f2bf(oacc[j][r] * inv[r]);
        }
    }
}

// ---------------------------------------------------------------------------
// LayerNorm over last dim (768), bf16 output. One block per row.
// ---------------------------------------------------------------------------
__global__ __launch_bounds__(256) void ln_kernel(
    const float* __restrict__ x, const float* __restrict__ g,
    const float* __restrict__ b, u16* __restrict__ out)
{
    long long row = blockIdx.x;
    const float* xr = x + row * DD;
    u16* orow = out + row * DD;
    int t = threadIdx.x;
    float vals[3];
    float s = 0.f, ss = 0.f;
    #pragma unroll
    for (int i = 0; i < 3; i++) {
        float v = xr[t + i * 256];
        vals[i] = v; s += v; ss += v * v;
    }
    __shared__ float rs[256], rss[256];
    rs[t] = s; rss[t] = ss; __syncthreads();
    for (int k = 128; k > 0; k >>= 1) {
        if (t < k) { rs[t] += rs[t + k]; rss[t] += rss[t + k]; }
        __syncthreads();
    }
    float mean = rs[0] * (1.0f / DD);
    float var = rss[0] * (1.0f / DD) - mean * mean;
    float inv = rsqrtf(var + 1e-5f);
    #pragma unroll
    for (int i = 0; i < 3; i++) {
        int d = t + i * 256;
        orow[d] = f2bf((vals[i] - mean) * inv * g[d] + b[d]);
    }
}

// ---------------------------------------------------------------------------
// Router part 1: partial column sums of x over T.
// ---------------------------------------------------------------------------
__global__ __launch_bounds__(256) void mean_part_kernel(
    const float* __restrict__ x, float* __restrict__ part)
{
    int b = blockIdx.x, dseg = blockIdx.y, rc = blockIdx.z;
    int d = dseg * 256 + threadIdx.x;
    const float* xb = x + (long long)b * TT * DD;
    float s = 0.f;
    int r0 = rc * 64;
    for (int r = r0; r < r0 + 64; ++r) s += xb[(long long)r * DD + d];
    part[((long long)b * 8 + rc) * DD + d] = s;
}

// ---------------------------------------------------------------------------
// Router part 2.
// ---------------------------------------------------------------------------
__global__ __launch_bounds__(128) void router_kernel(
    const float* __restrict__ part, const float* __restrict__ w1,
    const float* __restrict__ b1, const float* __restrict__ w2,
    const float* __restrict__ b2, int* __restrict__ idx)
{
    int b = blockIdx.x, t = threadIdx.x;
    __shared__ float xm[DD];
    __shared__ float h[128];
    __shared__ float logits[8];
    for (int i = t; i < DD; i += 128) {
        float s = 0.f;
        for (int rc = 0; rc < 8; ++rc) s += part[((long long)b * 8 + rc) * DD + i];
        xm[i] = s * (1.0f / TT);
    }
    __syncthreads();
    {
        float s = b1[t];
        const float* w = w1 + (long long)t * DD;
        for (int d = 0; d < DD; ++d) s += xm[d] * w[d];
        h[t] = gelu_exact(s);
    }
    __syncthreads();
    if (t < 8) {
        float s = b2[t];
        const float* w = w2 + t * 128;
        for (int d = 0; d < 128; ++d) s += h[d] * w[d];
        logits[t] = s;
    }
    __syncthreads();
    if (t == 0) {
        int bsix = 0;
        for (int i = 1; i < 4; i++) if (logits[i] > logits[bsix]) bsix = i;
        int btix = 4;
        for (int i = 5; i < 8; i++) if (logits[i] > logits[btix]) btix = i;
        idx[b] = bsix;
        idx[b + BB] = btix - 4;
    }
}

// ---------------------------------------------------------------------------
static void run_gemm2(hipStream_t stream,
    const u16* A, long long sAb, int lda,
    const u16* B, const int* bidx, long long sBexp, int ldb,
    void* C, long long sCb, int ldc,
    const float* bias, long long sBiasExp,
    const void* resid, long long sResB, int ldr,
    int act, int N, int K, int outbf, int resmode)
{
    dim3 grid(N / 128, 4, BB);
    if (outbf && resmode == 0)
        gemm_bf16_kernel<1, 0><<<grid, 256, 0, stream>>>(A, sAb, lda, B, bidx, sBexp, ldb,
            C, sCb, ldc, bias, sBiasExp, resid, sResB, ldr, act, N, K);
    else if (outbf)
        gemm_bf16_kernel<1, 2><<<grid, 256, 0, stream>>>(A, sAb, lda, B, bidx, sBexp, ldb,
            C, sCb, ldc, bias, sBiasExp, resid, sResB, ldr, act, N, K);
    else
        gemm_bf16_kernel<0, 1><<<grid, 256, 0, stream>>>(A, sAb, lda, B, bidx, sBexp, ldb,
            C, sCb, ldc, bias, sBiasExp, resid, sResB, ldr, act, N, K);
}

extern "C" void kernel_launch(void* const* d_in, const int* in_sizes, int n_in,
                              void* d_out, int out_size, void* d_ws, size_t ws_size,
                              hipStream_t stream)
{
    const float* x       = (const float*)d_in[0];
    const float* rw1     = (const float*)d_in[1];
    const float* rb1     = (const float*)d_in[2];
    const float* rw2     = (const float*)d_in[3];
    const float* rb2     = (const float*)d_in[4];
    const float* gs      = (const float*)d_in[5];
    const float* bs      = (const float*)d_in[6];
    const float* gt      = (const float*)d_in[7];
    const float* btt     = (const float*)d_in[8];
    const float* gm      = (const float*)d_in[9];
    const float* bm      = (const float*)d_in[10];
    const float* sp_wqkv = (const float*)d_in[11];
    const float* sp_bqkv = (const float*)d_in[12];
    const float* sp_wo   = (const float*)d_in[13];
    const float* sp_bo   = (const float*)d_in[14];
    const float* tp_wq   = (const float*)d_in[15];
    const float* tp_bq   = (const float*)d_in[16];
    const float* tp_wk   = (const float*)d_in[17];
    const float* tp_bk   = (const float*)d_in[18];
    const float* tp_wv   = (const float*)d_in[19];
    const float* tp_bv   = (const float*)d_in[20];
    const float* tp_wo   = (const float*)d_in[21];
    const float* tp_bo   = (const float*)d_in[22];
    const float* c_wqkv  = (const float*)d_in[23];
    const float* c_bqkv  = (const float*)d_in[24];
    const float* c_wo    = (const float*)d_in[25];
    const float* c_bo    = (const float*)d_in[26];
    const float* m_w1    = (const float*)d_in[27];
    const float* m_b1    = (const float*)d_in[28];
    const float* m_w2    = (const float*)d_in[29];
    const float* m_b2    = (const float*)d_in[30];
    float* out = (float*)d_out;

    float* ws = (float*)d_ws;
    size_t o = 0;
    float* part  = ws + o; o += (size_t)BB * 8 * DD;
    int*   idx   = (int*)(ws + o); o += 16;
    float* tpb   = ws + o; o += 4 * 2304;                     // packed temporal bias
    float* x1b   = ws + o; o += (size_t)4096 * DD;            // f32 (x + fused)
    u16* xnb   = (u16*)(ws + o); o += (size_t)4096 * DD / 2;  // LN out (bf16)
    u16* tmp1b = (u16*)(ws + o); o += (size_t)4096 * DD / 2;  // attention out
    u16* tmp2b = (u16*)(ws + o); o += (size_t)4096 * DD / 2;  // LN for mlp
    u16* soutb = (u16*)(ws + o); o += (size_t)4096 * DD / 2;  // spatial_out
    u16* toutb = (u16*)(ws + o); o += (size_t)4096 * DD / 2;  // temporal_out
    u16* qkvb  = (u16*)(ws + o); o += (size_t)4096 * 2304 / 2;// q|k|v packed bf16
    u16* yb    = (u16*)(ws + o); o += (size_t)4096 * 3072 / 2;// mlp hidden bf16
    u16* wpool = (u16*)(ws + o); o += (size_t)CUM10 / 2;      // bf16 weights

    u16* w_sp_qkv = wpool;
    u16* w_sp_wo  = wpool + CUM1;
    u16* w_tp_qkv = wpool + CUM2;   // interleaved [e][3*DD][DD]
    u16* w_tp_o   = wpool + CUM5;
    u16* w_c_qkv  = wpool + CUM6;
    u16* w_c_wo   = wpool + CUM7;
    u16* w_m1     = wpool + CUM8;
    u16* w_m2     = wpool + CUM9;

    int* idx_s = idx;
    int* idx_t = idx + BB;

    const long long sTD  = (long long)TT * DD;       // 512*768
    const long long sT3D = (long long)TT * 3 * DD;   // 512*2304
    const long long sT4D = (long long)TT * 4 * DD;   // 512*3072
    const float qk_scale = 1.0f / sqrtf((float)HDIM);

    // ---- weight convert (f32 -> bf16) + temporal bias pack ----
    cvt_kernel<<<(int)((CUM10 / 8 + 255) / 256), 256, 0, stream>>>(
        sp_wqkv, sp_wo, tp_wq, tp_wk, tp_wv, tp_wo, c_wqkv, c_wo, m_w1, m_w2, wpool);
    pack_tpb_kernel<<<36, 256, 0, stream>>>(tp_bq, tp_bk, tp_bv, tpb);

    // ---- router ----
    mean_part_kernel<<<dim3(BB, 3, 8), 256, 0, stream>>>(x, part);
    router_kernel<<<BB, 128, 0, stream>>>(part, rw1, rb1, rw2, rb2, idx);

    // ---- spatial branch ----
    ln_kernel<<<4096, 256, 0, stream>>>(x, gs, bs, xnb);
    // qkv = xn @ sp_wqkv[idx_s]^T + sp_bqkv[idx_s]
    run_gemm2(stream, xnb, sTD, DD, w_sp_qkv, idx_s, 3 * DDDD, DD,
              qkvb, sT3D, 3 * DD, sp_bqkv, 3 * DD, nullptr, 0, 0,
              0, 3 * DD, DD, 1, 0);
    attn_kernel<<<dim3(TT / 64, BB * HH), 256, 0, stream>>>(qkvb, tmp1b, 0, qk_scale);
    // spatial_out = O @ sp_wo[idx_s]^T + sp_bo[idx_s]
    run_gemm2(stream, tmp1b, sTD, DD, w_sp_wo, idx_s, DDDD, DD,
              soutb, sTD, DD, sp_bo, DD, nullptr, 0, 0,
              0, DD, DD, 1, 0);

    // ---- temporal branch ----
    ln_kernel<<<4096, 256, 0, stream>>>(x, gt, btt, xnb);
    // q|k|v = xt @ tp_wqkv[idx_t]^T + tpb[idx_t]   (single merged GEMM)
    run_gemm2(stream, xnb, sTD, DD, w_tp_qkv, idx_t, 3 * DDDD, DD,
              qkvb, sT3D, 3 * DD, tpb, 3 * DD, nullptr, 0, 0,
              0, 3 * DD, DD, 1, 0);
    attn_kernel<<<dim3(TT / 64, BB * HH), 256, 0, stream>>>(qkvb, tmp1b, 1, qk_scale);
    // temporal_out = xt + O @ tp_wo[idx_t]^T + tp_bo[idx_t]   (bf16 resid xnb)
    run_gemm2(stream, tmp1b, sTD, DD, w_tp_o, idx_t, DDDD, DD,
              toutb, sTD, DD, tp_bo, DD, xnb, sTD, DD,
              0, DD, DD, 1, 2);

    // ---- cross attention ----
    run_gemm2(stream, soutb, sTD, DD, w_c_qkv, nullptr, 0, DD,
              qkvb, sT3D, 3 * DD, c_bqkv, 0, nullptr, 0, 0,
              0, DD, DD, 1, 0);
    run_gemm2(stream, toutb, sTD, DD, w_c_qkv + DDDD, nullptr, 0, DD,
              qkvb + DD, sT3D, 3 * DD, c_bqkv + DD, 0, nullptr, 0, 0,
              0, 2 * DD, DD, 1, 0);
    attn_kernel<<<dim3(TT / 64, BB * HH), 256, 0, stream>>>(qkvb, tmp1b, 0, qk_scale);
    // x1 = x + (fused_attn @ cross_wo^T + cross_bo)   (f32 out, f32 resid)
    run_gemm2(stream, tmp1b, sTD, DD, w_c_wo, nullptr, 0, DD,
              x1b, sTD, DD, c_bo, 0, x, sTD, DD,
              0, DD, DD, 0, 1);

    // ---- MLP ----
    ln_kernel<<<4096, 256, 0, stream>>>(x1b, gm, bm, tmp2b);
    // y = gelu(ln @ mlp_w1^T + b1) -> bf16
    run_gemm2(stream, tmp2b, sTD, DD, w_m1, nullptr, 0, DD,
              yb, sT4D, 4 * DD, m_b1, 0, nullptr, 0, 0,
              1, 4 * DD, DD, 1, 0);
    // out = x1 + y @ mlp_w2^T + b2   (f32 out, f32 resid)
    run_gemm2(stream, yb, sT4D, 4 * DD, w_m2, nullptr, 0, 4 * DD,
              out, sTD, DD, m_b2, 0, x1b, sTD, DD,
              0, DD, 4 * DD, 0, 1);
}

// Round 4
// 811.295 us; speedup vs baseline: 1.6469x; 1.0262x over previous
//
#include <hip/hip_runtime.h>
#include <math.h>

// Problem constants
#define BB 8
#define TT 512
#define DD 768
#define HH 8
#define HDIM 96
#define DDDD 589824LL   // 768*768

typedef short s16x8 __attribute__((ext_vector_type(8)));
typedef float f32x4 __attribute__((ext_vector_type(4)));
typedef unsigned short u16;

__device__ inline unsigned short f2bf(float f) {
    union { float f; unsigned u; } v; v.f = f;
    unsigned u = v.u;
    unsigned r = (u + 0x7fffu + ((u >> 16) & 1u)) >> 16;
    return (unsigned short)r;
}

__device__ inline float bf2f(u16 h) {
    union { unsigned u; float f; } v; v.u = ((unsigned)h) << 16; return v.f;
}

__device__ inline float gelu_exact(float x) {
    return 0.5f * x * (1.0f + erff(x * 0.70710678118654752440f));
}

__device__ __forceinline__ void gload16(const void* g, void* l) {
    __builtin_amdgcn_global_load_lds(
        (const __attribute__((address_space(1))) unsigned int*)g,
        (__attribute__((address_space(3))) unsigned int*)l,
        16, 0, 0);
}

// ---------------------------------------------------------------------------
// Weight convert: f32 -> bf16 for all 10 weight tensors in one launch.
// tp_wq/wk/wv (tensors 2,3,4) are written INTERLEAVED per expert:
//   dest[CUM2 + e*3*DDDD + {0,1,2}*DDDD + r]  so temporal qkv is one GEMM.
// ---------------------------------------------------------------------------
#define CUM1  7077888LL
#define CUM2  9437184LL
#define CUM3  11796480LL
#define CUM4  14155776LL
#define CUM5  16515072LL
#define CUM6  18874368LL
#define CUM7  20643840LL
#define CUM8  21233664LL
#define CUM9  23592960LL
#define CUM10 25952256LL

__global__ __launch_bounds__(256) void cvt_kernel(
    const float* __restrict__ s0, const float* __restrict__ s1,
    const float* __restrict__ s2, const float* __restrict__ s3,
    const float* __restrict__ s4, const float* __restrict__ s5,
    const float* __restrict__ s6, const float* __restrict__ s7,
    const float* __restrict__ s8, const float* __restrict__ s9,
    u16* __restrict__ dpool)
{
    long long g = ((long long)blockIdx.x * 256 + threadIdx.x) * 8;
    if (g >= CUM10) return;
    const float* s; long long base;
    int tp = -1;
    if      (g < CUM1) { s = s0; base = 0; }
    else if (g < CUM2) { s = s1; base = CUM1; }
    else if (g < CUM3) { s = s2; base = CUM2; tp = 0; }
    else if (g < CUM4) { s = s3; base = CUM3; tp = 1; }
    else if (g < CUM5) { s = s4; base = CUM4; tp = 2; }
    else if (g < CUM6) { s = s5; base = CUM5; }
    else if (g < CUM7) { s = s6; base = CUM6; }
    else if (g < CUM8) { s = s7; base = CUM7; }
    else if (g < CUM9) { s = s8; base = CUM8; }
    else               { s = s9; base = CUM9; }
    long long i = g - base;
    long long d = g;
    if (tp >= 0) {
        long long e = i / DDDD, r = i - e * DDDD;
        d = CUM2 + e * 3 * DDDD + (long long)tp * DDDD + r;
    }
    float4 a = *(const float4*)(s + i);
    float4 b = *(const float4*)(s + i + 4);
    s16x8 o;
    o[0] = f2bf(a.x); o[1] = f2bf(a.y); o[2] = f2bf(a.z); o[3] = f2bf(a.w);
    o[4] = f2bf(b.x); o[5] = f2bf(b.y); o[6] = f2bf(b.z); o[7] = f2bf(b.w);
    *(s16x8*)(dpool + d) = o;
}

// pack temporal biases [4][2304] = bq|bk|bv
__global__ __launch_bounds__(256) void pack_tpb_kernel(
    const float* __restrict__ bq, const float* __restrict__ bk,
    const float* __restrict__ bv, float* __restrict__ dst)
{
    int t = blockIdx.x * 256 + threadIdx.x;
    if (t >= 4 * 2304) return;
    int e = t / 2304, n = t - e * 2304;
    float v = (n < 768) ? bq[e * 768 + n]
            : (n < 1536) ? bk[e * 768 + n - 768]
            : bv[e * 768 + n - 1536];
    dst[t] = v;
}

// ---------------------------------------------------------------------------
// bf16 GEMM: C[z] = A[z] * B^T (+bias) (gelu?) (+resid)
//   Tile 64x128 (MxN), BK=64, 4 waves each 32x64 via 2x4 MFMA 16x16x32.
//   DOUBLE-BUFFERED: prefetch slab t+1 via global_load_lds while computing
//   slab t; counted s_waitcnt vmcnt(6) + raw s_barrier (never drain to 0
//   in-loop).  LDS 2*(8+16) KB = 48 KB -> up to 3 blocks/CU.
//   LDS layout [kwin][rows][8]: conflict-free ds_read_b128, linear
//   global_load_lds destinations.
//   OUT_BF16: C dtype. RES_MODE: 0 none, 1 f32 resid, 2 bf16 resid.
//   Requires M=512, N%128==0, K%64==0.
// ---------------------------------------------------------------------------
#define ABUF (8 * 64 * 8)
#define BBUF (8 * 128 * 8)

template<int OUT_BF16, int RES_MODE>
__global__ __launch_bounds__(256) void gemm_bf16_kernel(
    const u16* __restrict__ A, long long sAb, int lda,
    const u16* __restrict__ B, const int* __restrict__ bidx, long long sBexp, int ldb,
    void* __restrict__ Cv, long long sCb, int ldc,
    const float* __restrict__ bias, long long sBiasExp,
    const void* __restrict__ residv, long long sResB, int ldr,
    int act, int N, int K)
{
    int zb = blockIdx.z;
    const u16* Ab = A + zb * sAb;
    const u16* Bb = B + (bidx ? (long long)bidx[zb] * sBexp : 0);
    const float* biasb = bias ? (bias + (bidx ? (long long)bidx[zb] * sBiasExp : 0)) : nullptr;

    int n0 = blockIdx.x * 128;
    int m0 = blockIdx.y * 64;

    __shared__ __align__(16) u16 As[2][ABUF];   //  8 KB each
    __shared__ __align__(16) u16 Bs[2][BBUF];   // 16 KB each

    int tid = threadIdx.x;
    int wave = tid >> 6, lane = tid & 63;
    int wr = wave >> 1, wc = wave & 1;
    int lrow = lane & 15, lkg = lane >> 4;

    f32x4 acc[2][4];
    #pragma unroll
    for (int i = 0; i < 2; i++)
        #pragma unroll
        for (int j = 0; j < 4; j++)
            acc[i][j] = (f32x4){0.f, 0.f, 0.f, 0.f};

    // staging geometry: A slot s (0..511): row=s&63, kw=s>>6; thread does
    // s=tid (kw 0..3) and s=tid+256 (kw+4). B slot s (0..1023): row=s&127,
    // kw=s>>7; thread does s=tid,+256,+512,+768 (kw+0/2/4/6).
    int arow = tid & 63,  akw = tid >> 6;
    int brow = tid & 127, bkw = tid >> 7;
    const u16* ag = Ab + (long long)(m0 + arow) * lda + akw * 8;
    const u16* bg = Bb + (long long)(n0 + brow) * ldb + bkw * 8;
    u16* asl = &As[0][(akw * 64 + arow) * 8];
    u16* bsl = &Bs[0][(bkw * 128 + brow) * 8];

    int nK = K >> 6;
    // prologue: stage slab 0 into buf 0
    gload16(ag, asl);      gload16(ag + 32, asl + 4 * 64 * 8);
    gload16(bg, bsl);      gload16(bg + 16, bsl + 2 * 128 * 8);
    gload16(bg + 32, bsl + 4 * 128 * 8);
    gload16(bg + 48, bsl + 6 * 128 * 8);

    for (int kt = 0; kt < nK; ++kt) {
        int cur = kt & 1;
        if (kt + 1 < nK) {
            // prefetch slab kt+1 into the other buffer
            const u16* a = ag + (kt + 1) * 64;
            const u16* b = bg + (kt + 1) * 64;
            u16* ad = asl + (cur ^ 1) * ABUF;
            u16* bd = bsl + (cur ^ 1) * BBUF;
            gload16(a, ad);      gload16(a + 32, ad + 4 * 64 * 8);
            gload16(b, bd);      gload16(b + 16, bd + 2 * 128 * 8);
            gload16(b + 32, bd + 4 * 128 * 8);
            gload16(b + 48, bd + 6 * 128 * 8);
            asm volatile("s_waitcnt vmcnt(6)" ::: "memory");  // slab kt landed
        } else {
            asm volatile("s_waitcnt vmcnt(0)" ::: "memory");
        }
        __builtin_amdgcn_s_barrier();        // all waves' slab-kt loads landed
        __builtin_amdgcn_sched_barrier(0);   // don't hoist ds_read above

        const u16* Asb = &As[cur][0];
        const u16* Bsb = &Bs[cur][0];
        #pragma unroll
        for (int kk = 0; kk < 2; ++kk) {
            s16x8 af[2], bf[4];
            #pragma unroll
            for (int i = 0; i < 2; ++i)
                af[i] = *(const s16x8*)&Asb[((kk * 4 + lkg) * 64 + wr * 32 + i * 16 + lrow) * 8];
            #pragma unroll
            for (int j = 0; j < 4; ++j)
                bf[j] = *(const s16x8*)&Bsb[((kk * 4 + lkg) * 128 + wc * 64 + j * 16 + lrow) * 8];
            #pragma unroll
            for (int i = 0; i < 2; ++i)
                #pragma unroll
                for (int j = 0; j < 4; ++j)
                    acc[i][j] = __builtin_amdgcn_mfma_f32_16x16x32_bf16(af[i], bf[j], acc[i][j], 0, 0, 0);
        }
        __builtin_amdgcn_s_barrier();        // reads done -> buffer reusable
    }

    // epilogue: C/D layout col=lane&15, row=(lane>>4)*4+reg
    float* Cf = (float*)Cv + zb * sCb;
    u16* Ch = (u16*)Cv + zb * sCb;
    const float* Rf = (const float*)residv + zb * sResB;
    const u16* Rh = (const u16*)residv + zb * sResB;
    int col16 = lane & 15;
    int rq = (lane >> 4) * 4;
    #pragma unroll
    for (int j = 0; j < 4; ++j) {
        int n = n0 + wc * 64 + j * 16 + col16;
        float bv = biasb ? biasb[n] : 0.0f;
        #pragma unroll
        for (int i = 0; i < 2; ++i) {
            #pragma unroll
            for (int r = 0; r < 4; ++r) {
                int m = m0 + wr * 32 + i * 16 + rq + r;
                float v = acc[i][j][r] + bv;
                if (act == 1) v = gelu_exact(v);
                if (RES_MODE == 1) v += Rf[(long long)m * ldr + n];
                if (RES_MODE == 2) v += bf2f(Rh[(long long)m * ldr + n]);
                if (OUT_BF16) Ch[(long long)m * ldc + n] = f2bf(v);
                else          Cf[(long long)m * ldc + n] = v;
            }
        }
    }
}

// ---------------------------------------------------------------------------
// Fused flash attention (bf16 I/O): O = softmax(scale * Q K^T [causal]) V.
// QKV bf16 packed [B][T][3*D]; Out bf16 [B][T][D].
// Grid (T/64, B*H), 256 threads = 4 waves, each wave owns 16 query rows.
// ---------------------------------------------------------------------------
__global__ __launch_bounds__(256, 2) void attn_kernel(
    const u16* __restrict__ QKV, u16* __restrict__ Out,
    int causal, float scale)
{
    int qt = blockIdx.x;
    int bh = blockIdx.y;
    int b = bh >> 3;
    int h = bh & 7;
    const u16* Qb = QKV + (long long)b * TT * 3 * DD + (long long)h * HDIM;
    const u16* Kb = Qb + DD;
    const u16* Vb = Qb + 2 * DD;
    u16* Ob = Out + (long long)b * TT * DD + (long long)h * HDIM;

    __shared__ __align__(16) u16 Qs[64 * 104];  // [qrow][d], stride 104
    __shared__ __align__(16) u16 Ks[64 * 104];
    __shared__ __align__(16) u16 Vs[96 * 72];   // [d][krow], stride 72
    __shared__ __align__(16) u16 Ps[64 * 72];   // [qrow][krow]

    int tid = threadIdx.x;
    int wave = tid >> 6;
    int lane = tid & 63;
    int col16 = lane & 15;
    int lkg = lane >> 4;
    int lk = lkg * 8;
    int m0 = qt * 64;

    // ---- stage Q tile 64x96 bf16 (768 x 8-elem slots, 3/thread) ----
    #pragma unroll
    for (int it = 0; it < 3; ++it) {
        int s = tid + it * 256;
        int r = s / 12, c8 = (s % 12) * 8;
        *(s16x8*)&Qs[r * 104 + c8] = *(const s16x8*)(Qb + (long long)(m0 + r) * (3 * DD) + c8);
    }
    __syncthreads();

    s16x8 qf[3];
    #pragma unroll
    for (int kk = 0; kk < 3; ++kk)
        qf[kk] = *(const s16x8*)&Qs[(wave * 16 + col16) * 104 + kk * 32 + lk];

    // ---- QK^T ----
    f32x4 acc[32];
    #pragma unroll
    for (int n = 0; n < 32; ++n) acc[n] = (f32x4){0.f, 0.f, 0.f, 0.f};

    #pragma unroll
    for (int kt = 0; kt < 8; ++kt) {
        #pragma unroll
        for (int it = 0; it < 3; ++it) {
            int s = tid + it * 256;
            int r = s / 12, c8 = (s % 12) * 8;
            *(s16x8*)&Ks[r * 104 + c8] = *(const s16x8*)(Kb + (long long)(kt * 64 + r) * (3 * DD) + c8);
        }
        __syncthreads();
        #pragma unroll
        for (int kk = 0; kk < 3; ++kk) {
            #pragma unroll
            for (int j = 0; j < 4; ++j) {
                s16x8 bfr = *(const s16x8*)&Ks[(j * 16 + col16) * 104 + kk * 32 + lk];
                acc[kt * 4 + j] = __builtin_amdgcn_mfma_f32_16x16x32_bf16(qf[kk], bfr, acc[kt * 4 + j], 0, 0, 0);
            }
        }
        __syncthreads();
    }

    // ---- softmax (registers + shfl only) ----
    int rowbase = m0 + wave * 16 + lkg * 4;
    float mx[4];
    #pragma unroll
    for (int r = 0; r < 4; ++r) mx[r] = -3.0e38f;
    #pragma unroll
    for (int n = 0; n < 32; ++n) {
        int colg = n * 16 + col16;
        #pragma unroll
        for (int r = 0; r < 4; ++r) {
            float v = acc[n][r] * scale;
            if (causal && colg > rowbase + r) v = -3.0e38f;
            acc[n][r] = v;
            mx[r] = fmaxf(mx[r], v);
        }
    }
    #pragma unroll
    for (int m = 1; m <= 8; m <<= 1)
        #pragma unroll
        for (int r = 0; r < 4; ++r)
            mx[r] = fmaxf(mx[r], __shfl_xor(mx[r], m, 64));

    float sum[4] = {0.f, 0.f, 0.f, 0.f};
    #pragma unroll
    for (int n = 0; n < 32; ++n) {
        #pragma unroll
        for (int r = 0; r < 4; ++r) {
            float e = __expf(acc[n][r] - mx[r]);
            acc[n][r] = e;
            sum[r] += e;
        }
    }
    #pragma unroll
    for (int m = 1; m <= 8; m <<= 1)
        #pragma unroll
        for (int r = 0; r < 4; ++r)
            sum[r] += __shfl_xor(sum[r], m, 64);
    float inv[4];
    #pragma unroll
    for (int r = 0; r < 4; ++r) inv[r] = 1.0f / sum[r];

    // ---- PV ----
    f32x4 oacc[6];
    #pragma unroll
    for (int j = 0; j < 6; ++j) oacc[j] = (f32x4){0.f, 0.f, 0.f, 0.f};

    #pragma unroll
    for (int kt = 0; kt < 8; ++kt) {
        __syncthreads();
        // write P strip (unnormalized e, bf16)
        #pragma unroll
        for (int j = 0; j < 4; ++j) {
            #pragma unroll
            for (int r = 0; r < 4; ++r)
                Ps[(wave * 16 + lkg * 4 + r) * 72 + j * 16 + col16] = f2bf(acc[kt * 4 + j][r]);
        }
        // stage V tile transposed: V[kt*64+key][d] -> Vs[d][key]
        #pragma unroll
        for (int it = 0; it < 3; ++it) {
            int s = tid + it * 256;
            int key = s / 12, c8 = (s % 12) * 8;
            s16x8 v = *(const s16x8*)(Vb + (long long)(kt * 64 + key) * (3 * DD) + c8);
            #pragma unroll
            for (int e = 0; e < 8; ++e)
                Vs[(c8 + e) * 72 + key] = (u16)v[e];
        }
        __syncthreads();
        #pragma unroll
        for (int kk = 0; kk < 2; ++kk) {
            s16x8 pf = *(const s16x8*)&Ps[(wave * 16 + col16) * 72 + kk * 32 + lk];
            #pragma unroll
            for (int j = 0; j < 6; ++j) {
                s16x8 vf = *(const s16x8*)&Vs[(j * 16 + col16) * 72 + kk * 32 + lk];
                oacc[j] = __builtin_amdgcn_mfma_f32_16x16x32_bf16(pf, vf, oacc[j], 0, 0, 0);
            }
        }
    }

    // ---- epilogue ----
    int rquad = lkg * 4;
    #pragma unroll
    for (int j = 0; j < 6; ++j) {
        int d = j * 16 + col16;
        #pragma unroll
        for (int r = 0; r < 4; ++r) {
            int row = m0 + wave * 16 + rquad + r;
            Ob[(long long)row * DD + d] = f2bf(oacc[j][r] * inv[r]);
        }
    }
}

// ---------------------------------------------------------------------------
// LayerNorm over last dim (768), bf16 output. One block per row.
// ---------------------------------------------------------------------------
__global__ __launch_bounds__(256) void ln_kernel(
    const float* __restrict__ x, const float* __restrict__ g,
    const float* __restrict__ b, u16* __restrict__ out)
{
    long long row = blockIdx.x;
    const float* xr = x + row * DD;
    u16* orow = out + row * DD;
    int t = threadIdx.x;
    float vals[3];
    float s = 0.f, ss = 0.f;
    #pragma unroll
    for (int i = 0; i < 3; i++) {
        float v = xr[t + i * 256];
        vals[i] = v; s += v; ss += v * v;
    }
    __shared__ float rs[256], rss[256];
    rs[t] = s; rss[t] = ss; __syncthreads();
    for (int k = 128; k > 0; k >>= 1) {
        if (t < k) { rs[t] += rs[t + k]; rss[t] += rss[t + k]; }
        __syncthreads();
    }
    float mean = rs[0] * (1.0f / DD);
    float var = rss[0] * (1.0f / DD) - mean * mean;
    float inv = rsqrtf(var + 1e-5f);
    #pragma unroll
    for (int i = 0; i < 3; i++) {
        int d = t + i * 256;
        orow[d] = f2bf((vals[i] - mean) * inv * g[d] + b[d]);
    }
}

// ---------------------------------------------------------------------------
// Router part 1: partial column sums of x over T.
// ---------------------------------------------------------------------------
__global__ __launch_bounds__(256) void mean_part_kernel(
    const float* __restrict__ x, float* __restrict__ part)
{
    int b = blockIdx.x, dseg = blockIdx.y, rc = blockIdx.z;
    int d = dseg * 256 + threadIdx.x;
    const float* xb = x + (long long)b * TT * DD;
    float s = 0.f;
    int r0 = rc * 64;
    for (int r = r0; r < r0 + 64; ++r) s += xb[(long long)r * DD + d];
    part[((long long)b * 8 + rc) * DD + d] = s;
}

// ---------------------------------------------------------------------------
// Router part 2.
// ---------------------------------------------------------------------------
__global__ __launch_bounds__(128) void router_kernel(
    const float* __restrict__ part, const float* __restrict__ w1,
    const float* __restrict__ b1, const float* __restrict__ w2,
    const float* __restrict__ b2, int* __restrict__ idx)
{
    int b = blockIdx.x, t = threadIdx.x;
    __shared__ float xm[DD];
    __shared__ float h[128];
    __shared__ float logits[8];
    for (int i = t; i < DD; i += 128) {
        float s = 0.f;
        for (int rc = 0; rc < 8; ++rc) s += part[((long long)b * 8 + rc) * DD + i];
        xm[i] = s * (1.0f / TT);
    }
    __syncthreads();
    {
        float s = b1[t];
        const float* w = w1 + (long long)t * DD;
        for (int d = 0; d < DD; ++d) s += xm[d] * w[d];
        h[t] = gelu_exact(s);
    }
    __syncthreads();
    if (t < 8) {
        float s = b2[t];
        const float* w = w2 + t * 128;
        for (int d = 0; d < 128; ++d) s += h[d] * w[d];
        logits[t] = s;
    }
    __syncthreads();
    if (t == 0) {
        int bsix = 0;
        for (int i = 1; i < 4; i++) if (logits[i] > logits[bsix]) bsix = i;
        int btix = 4;
        for (int i = 5; i < 8; i++) if (logits[i] > logits[btix]) btix = i;
        idx[b] = bsix;
        idx[b + BB] = btix - 4;
    }
}

// ---------------------------------------------------------------------------
static void run_gemm2(hipStream_t stream,
    const u16* A, long long sAb, int lda,
    const u16* B, const int* bidx, long long sBexp, int ldb,
    void* C, long long sCb, int ldc,
    const float* bias, long long sBiasExp,
    const void* resid, long long sResB, int ldr,
    int act, int N, int K, int outbf, int resmode)
{
    dim3 grid(N / 128, 8, BB);
    if (outbf && resmode == 0)
        gemm_bf16_kernel<1, 0><<<grid, 256, 0, stream>>>(A, sAb, lda, B, bidx, sBexp, ldb,
            C, sCb, ldc, bias, sBiasExp, resid, sResB, ldr, act, N, K);
    else if (outbf)
        gemm_bf16_kernel<1, 2><<<grid, 256, 0, stream>>>(A, sAb, lda, B, bidx, sBexp, ldb,
            C, sCb, ldc, bias, sBiasExp, resid, sResB, ldr, act, N, K);
    else
        gemm_bf16_kernel<0, 1><<<grid, 256, 0, stream>>>(A, sAb, lda, B, bidx, sBexp, ldb,
            C, sCb, ldc, bias, sBiasExp, resid, sResB, ldr, act, N, K);
}

extern "C" void kernel_launch(void* const* d_in, const int* in_sizes, int n_in,
                              void* d_out, int out_size, void* d_ws, size_t ws_size,
                              hipStream_t stream)
{
    const float* x       = (const float*)d_in[0];
    const float* rw1     = (const float*)d_in[1];
    const float* rb1     = (const float*)d_in[2];
    const float* rw2     = (const float*)d_in[3];
    const float* rb2     = (const float*)d_in[4];
    const float* gs      = (const float*)d_in[5];
    const float* bs      = (const float*)d_in[6];
    const float* gt      = (const float*)d_in[7];
    const float* btt     = (const float*)d_in[8];
    const float* gm      = (const float*)d_in[9];
    const float* bm      = (const float*)d_in[10];
    const float* sp_wqkv = (const float*)d_in[11];
    const float* sp_bqkv = (const float*)d_in[12];
    const float* sp_wo   = (const float*)d_in[13];
    const float* sp_bo   = (const float*)d_in[14];
    const float* tp_wq   = (const float*)d_in[15];
    const float* tp_bq   = (const float*)d_in[16];
    const float* tp_wk   = (const float*)d_in[17];
    const float* tp_bk   = (const float*)d_in[18];
    const float* tp_wv   = (const float*)d_in[19];
    const float* tp_bv   = (const float*)d_in[20];
    const float* tp_wo   = (const float*)d_in[21];
    const float* tp_bo   = (const float*)d_in[22];
    const float* c_wqkv  = (const float*)d_in[23];
    const float* c_bqkv  = (const float*)d_in[24];
    const float* c_wo    = (const float*)d_in[25];
    const float* c_bo    = (const float*)d_in[26];
    const float* m_w1    = (const float*)d_in[27];
    const float* m_b1    = (const float*)d_in[28];
    const float* m_w2    = (const float*)d_in[29];
    const float* m_b2    = (const float*)d_in[30];
    float* out = (float*)d_out;

    float* ws = (float*)d_ws;
    size_t o = 0;
    float* part  = ws + o; o += (size_t)BB * 8 * DD;
    int*   idx   = (int*)(ws + o); o += 16;
    float* tpb   = ws + o; o += 4 * 2304;                     // packed temporal bias
    float* x1b   = ws + o; o += (size_t)4096 * DD;            // f32 (x + fused)
    u16* xnb   = (u16*)(ws + o); o += (size_t)4096 * DD / 2;  // LN out (bf16)
    u16* tmp1b = (u16*)(ws + o); o += (size_t)4096 * DD / 2;  // attention out
    u16* tmp2b = (u16*)(ws + o); o += (size_t)4096 * DD / 2;  // LN for mlp
    u16* soutb = (u16*)(ws + o); o += (size_t)4096 * DD / 2;  // spatial_out
    u16* toutb = (u16*)(ws + o); o += (size_t)4096 * DD / 2;  // temporal_out
    u16* qkvb  = (u16*)(ws + o); o += (size_t)4096 * 2304 / 2;// q|k|v packed bf16
    u16* yb    = (u16*)(ws + o); o += (size_t)4096 * 3072 / 2;// mlp hidden bf16
    u16* wpool = (u16*)(ws + o); o += (size_t)CUM10 / 2;      // bf16 weights

    u16* w_sp_qkv = wpool;
    u16* w_sp_wo  = wpool + CUM1;
    u16* w_tp_qkv = wpool + CUM2;   // interleaved [e][3*DD][DD]
    u16* w_tp_o   = wpool + CUM5;
    u16* w_c_qkv  = wpool + CUM6;
    u16* w_c_wo   = wpool + CUM7;
    u16* w_m1     = wpool + CUM8;
    u16* w_m2     = wpool + CUM9;

    int* idx_s = idx;
    int* idx_t = idx + BB;

    const long long sTD  = (long long)TT * DD;       // 512*768
    const long long sT3D = (long long)TT * 3 * DD;   // 512*2304
    const long long sT4D = (long long)TT * 4 * DD;   // 512*3072
    const float qk_scale = 1.0f / sqrtf((float)HDIM);

    // ---- weight convert (f32 -> bf16) + temporal bias pack ----
    cvt_kernel<<<(int)((CUM10 / 8 + 255) / 256), 256, 0, stream>>>(
        sp_wqkv, sp_wo, tp_wq, tp_wk, tp_wv, tp_wo, c_wqkv, c_wo, m_w1, m_w2, wpool);
    pack_tpb_kernel<<<36, 256, 0, stream>>>(tp_bq, tp_bk, tp_bv, tpb);

    // ---- router ----
    mean_part_kernel<<<dim3(BB, 3, 8), 256, 0, stream>>>(x, part);
    router_kernel<<<BB, 128, 0, stream>>>(part, rw1, rb1, rw2, rb2, idx);

    // ---- spatial branch ----
    ln_kernel<<<4096, 256, 0, stream>>>(x, gs, bs, xnb);
    // qkv = xn @ sp_wqkv[idx_s]^T + sp_bqkv[idx_s]
    run_gemm2(stream, xnb, sTD, DD, w_sp_qkv, idx_s, 3 * DDDD, DD,
              qkvb, sT3D, 3 * DD, sp_bqkv, 3 * DD, nullptr, 0, 0,
              0, 3 * DD, DD, 1, 0);
    attn_kernel<<<dim3(TT / 64, BB * HH), 256, 0, stream>>>(qkvb, tmp1b, 0, qk_scale);
    // spatial_out = O @ sp_wo[idx_s]^T + sp_bo[idx_s]
    run_gemm2(stream, tmp1b, sTD, DD, w_sp_wo, idx_s, DDDD, DD,
              soutb, sTD, DD, sp_bo, DD, nullptr, 0, 0,
              0, DD, DD, 1, 0);

    // ---- temporal branch ----
    ln_kernel<<<4096, 256, 0, stream>>>(x, gt, btt, xnb);
    // q|k|v = xt @ tp_wqkv[idx_t]^T + tpb[idx_t]   (single merged GEMM)
    run_gemm2(stream, xnb, sTD, DD, w_tp_qkv, idx_t, 3 * DDDD, DD,
              qkvb, sT3D, 3 * DD, tpb, 3 * DD, nullptr, 0, 0,
              0, 3 * DD, DD, 1, 0);
    attn_kernel<<<dim3(TT / 64, BB * HH), 256, 0, stream>>>(qkvb, tmp1b, 1, qk_scale);
    // temporal_out = xt + O @ tp_wo[idx_t]^T + tp_bo[idx_t]   (bf16 resid xnb)
    run_gemm2(stream, tmp1b, sTD, DD, w_tp_o, idx_t, DDDD, DD,
              toutb, sTD, DD, tp_bo, DD, xnb, sTD, DD,
              0, DD, DD, 1, 2);

    // ---- cross attention ----
    run_gemm2(stream, soutb, sTD, DD, w_c_qkv, nullptr, 0, DD,
              qkvb, sT3D, 3 * DD, c_bqkv, 0, nullptr, 0, 0,
              0, DD, DD, 1, 0);
    run_gemm2(stream, toutb, sTD, DD, w_c_qkv + DDDD, nullptr, 0, DD,
              qkvb + DD, sT3D, 3 * DD, c_bqkv + DD, 0, nullptr, 0, 0,
              0, 2 * DD, DD, 1, 0);
    attn_kernel<<<dim3(TT / 64, BB * HH), 256, 0, stream>>>(qkvb, tmp1b, 0, qk_scale);
    // x1 = x + (fused_attn @ cross_wo^T + cross_bo)   (f32 out, f32 resid)
    run_gemm2(stream, tmp1b, sTD, DD, w_c_wo, nullptr, 0, DD,
              x1b, sTD, DD, c_bo, 0, x, sTD, DD,
              0, DD, DD, 0, 1);

    // ---- MLP ----
    ln_kernel<<<4096, 256, 0, stream>>>(x1b, gm, bm, tmp2b);
    // y = gelu(ln @ mlp_w1^T + b1) -> bf16
    run_gemm2(stream, tmp2b, sTD, DD, w_m1, nullptr, 0, DD,
              yb, sT4D, 4 * DD, m_b1, 0, nullptr, 0, 0,
              1, 4 * DD, DD, 1, 0);
    // out = x1 + y @ mlp_w2^T + b2   (f32 out, f32 resid)
    run_gemm2(stream, yb, sT4D, 4 * DD, w_m2, nullptr, 0, 4 * DD,
              out, sTD, DD, m_b2, 0, x1b, sTD, DD,
              0, DD, 4 * DD, 0, 1);
}

// Round 5
// 793.864 us; speedup vs baseline: 1.6830x; 1.0220x over previous
//
#include <hip/hip_runtime.h>
#include <math.h>

// Problem constants
#define BB 8
#define TT 512
#define DD 768
#define HH 8
#define HDIM 96
#define DDDD 589824LL   // 768*768

typedef short s16x8 __attribute__((ext_vector_type(8)));
typedef float f32x4 __attribute__((ext_vector_type(4)));
typedef unsigned short u16;

__device__ inline unsigned short f2bf(float f) {
    union { float f; unsigned u; } v; v.f = f;
    unsigned u = v.u;
    unsigned r = (u + 0x7fffu + ((u >> 16) & 1u)) >> 16;
    return (unsigned short)r;
}

__device__ inline float bf2f(u16 h) {
    union { unsigned u; float f; } v; v.u = ((unsigned)h) << 16; return v.f;
}

__device__ inline float gelu_exact(float x) {
    return 0.5f * x * (1.0f + erff(x * 0.70710678118654752440f));
}

__device__ __forceinline__ void gload16(const void* g, void* l) {
    __builtin_amdgcn_global_load_lds(
        (const __attribute__((address_space(1))) unsigned int*)g,
        (__attribute__((address_space(3))) unsigned int*)l,
        16, 0, 0);
}

// ---------------------------------------------------------------------------
// Weight convert: f32 -> bf16 for all 10 weight tensors in one launch.
// tp_wq/wk/wv (tensors 2,3,4) are written INTERLEAVED per expert:
//   dest[CUM2 + e*3*DDDD + {0,1,2}*DDDD + r]  so temporal qkv is one GEMM.
// ---------------------------------------------------------------------------
#define CUM1  7077888LL
#define CUM2  9437184LL
#define CUM3  11796480LL
#define CUM4  14155776LL
#define CUM5  16515072LL
#define CUM6  18874368LL
#define CUM7  20643840LL
#define CUM8  21233664LL
#define CUM9  23592960LL
#define CUM10 25952256LL

__global__ __launch_bounds__(256) void cvt_kernel(
    const float* __restrict__ s0, const float* __restrict__ s1,
    const float* __restrict__ s2, const float* __restrict__ s3,
    const float* __restrict__ s4, const float* __restrict__ s5,
    const float* __restrict__ s6, const float* __restrict__ s7,
    const float* __restrict__ s8, const float* __restrict__ s9,
    u16* __restrict__ dpool)
{
    long long g = ((long long)blockIdx.x * 256 + threadIdx.x) * 8;
    if (g >= CUM10) return;
    const float* s; long long base;
    int tp = -1;
    if      (g < CUM1) { s = s0; base = 0; }
    else if (g < CUM2) { s = s1; base = CUM1; }
    else if (g < CUM3) { s = s2; base = CUM2; tp = 0; }
    else if (g < CUM4) { s = s3; base = CUM3; tp = 1; }
    else if (g < CUM5) { s = s4; base = CUM4; tp = 2; }
    else if (g < CUM6) { s = s5; base = CUM5; }
    else if (g < CUM7) { s = s6; base = CUM6; }
    else if (g < CUM8) { s = s7; base = CUM7; }
    else if (g < CUM9) { s = s8; base = CUM8; }
    else               { s = s9; base = CUM9; }
    long long i = g - base;
    long long d = g;
    if (tp >= 0) {
        long long e = i / DDDD, r = i - e * DDDD;
        d = CUM2 + e * 3 * DDDD + (long long)tp * DDDD + r;
    }
    float4 a = *(const float4*)(s + i);
    float4 b = *(const float4*)(s + i + 4);
    s16x8 o;
    o[0] = f2bf(a.x); o[1] = f2bf(a.y); o[2] = f2bf(a.z); o[3] = f2bf(a.w);
    o[4] = f2bf(b.x); o[5] = f2bf(b.y); o[6] = f2bf(b.z); o[7] = f2bf(b.w);
    *(s16x8*)(dpool + d) = o;
}

// pack temporal biases [4][2304] = bq|bk|bv
__global__ __launch_bounds__(256) void pack_tpb_kernel(
    const float* __restrict__ bq, const float* __restrict__ bk,
    const float* __restrict__ bv, float* __restrict__ dst)
{
    int t = blockIdx.x * 256 + threadIdx.x;
    if (t >= 4 * 2304) return;
    int e = t / 2304, n = t - e * 2304;
    float v = (n < 768) ? bq[e * 768 + n]
            : (n < 1536) ? bk[e * 768 + n - 768]
            : bv[e * 768 + n - 1536];
    dst[t] = v;
}

// ---------------------------------------------------------------------------
// bf16 GEMM: C[z] = A[z] * B^T (+bias) (gelu?) (+resid)
//   Tile 64x128 (MxN), BK=32, 4 waves each 32x64 via 2x4 MFMA 16x16x32.
//   4-SLAB RING PIPELINE (depth 3): prologue issues slabs 0..2; iter kt
//   waits vmcnt(6) [slab kt landed, kt+1/kt+2 in flight], one s_barrier,
//   issues slab kt+3 into the buffer slab kt-1 vacated, computes slab kt.
//   Never drains vmcnt to 0 until the tail. LDS 4*(4+8) KB = 48 KB ->
//   3 blocks/CU; combined latency cover ~9 steps.
//   LDS layout [kw][rows][8]: conflict-free ds_read_b128, linear
//   global_load_lds destinations (slot = tid*16B).
//   OUT_BF16: C dtype. RES_MODE: 0 none, 1 f32 resid, 2 bf16 resid.
//   Requires M=512, N%128==0, K%32==0, K/32 >= 4.
// ---------------------------------------------------------------------------
#define SLABA (4 * 64 * 8)    // 2048 elems = 4 KB
#define SLABB (4 * 128 * 8)   // 4096 elems = 8 KB

template<int OUT_BF16, int RES_MODE>
__global__ __launch_bounds__(256) void gemm_bf16_kernel(
    const u16* __restrict__ A, long long sAb, int lda,
    const u16* __restrict__ B, const int* __restrict__ bidx, long long sBexp, int ldb,
    void* __restrict__ Cv, long long sCb, int ldc,
    const float* __restrict__ bias, long long sBiasExp,
    const void* __restrict__ residv, long long sResB, int ldr,
    int act, int N, int K)
{
    int zb = blockIdx.z;
    const u16* Ab = A + zb * sAb;
    const u16* Bb = B + (bidx ? (long long)bidx[zb] * sBexp : 0);
    const float* biasb = bias ? (bias + (bidx ? (long long)bidx[zb] * sBiasExp : 0)) : nullptr;

    int n0 = blockIdx.x * 128;
    int m0 = blockIdx.y * 64;

    __shared__ __align__(16) u16 As[4][SLABA];   // 16 KB
    __shared__ __align__(16) u16 Bs[4][SLABB];   // 32 KB

    int tid = threadIdx.x;
    int wave = tid >> 6, lane = tid & 63;
    int wr = wave >> 1, wc = wave & 1;
    int lrow = lane & 15, lkg = lane >> 4;

    f32x4 acc[2][4];
    #pragma unroll
    for (int i = 0; i < 2; i++)
        #pragma unroll
        for (int j = 0; j < 4; j++)
            acc[i][j] = (f32x4){0.f, 0.f, 0.f, 0.f};

    // staging geometry (per slab, 3 loads/thread):
    //   A: slot tid     -> row=tid&63,  kw=tid>>6 (0..3)
    //   B: slot tid     -> row=tid&127, kw=tid>>7 (0..1)
    //      slot tid+256 -> same row,    kw+2      (2..3)
    int arow = tid & 63,  akw = tid >> 6;
    int brow = tid & 127, bkw = tid >> 7;
    const u16* ag  = Ab + (long long)(m0 + arow) * lda + akw * 8;
    const u16* bg0 = Bb + (long long)(n0 + brow) * ldb + bkw * 8;
    const u16* bg1 = bg0 + 16;                    // kw+2
    u16* al  = (u16*)As + tid * 8;                // per-slab offset added below
    u16* bl0 = (u16*)Bs + tid * 8;
    u16* bl1 = (u16*)Bs + (tid + 256) * 8;

    auto stage = [&](int slab, int buf) {
        const u16* a  = ag  + slab * 32;
        const u16* b0 = bg0 + slab * 32;
        const u16* b1 = bg1 + slab * 32;
        gload16(a,  al  + buf * SLABA);
        gload16(b0, bl0 + buf * SLABB);
        gload16(b1, bl1 + buf * SLABB);
    };

    int nK = K >> 5;
    // prologue: slabs 0,1,2 into bufs 0,1,2  (9 loads outstanding)
    stage(0, 0);
    stage(1, 1);
    stage(2, 2);

    for (int kt = 0; kt < nK; ++kt) {
        // wait for own slab-kt loads (outstanding: kt..kt+2 -> keep 6)
        if (kt + 2 < nK)      asm volatile("s_waitcnt vmcnt(6)" ::: "memory");
        else if (kt + 1 < nK) asm volatile("s_waitcnt vmcnt(3)" ::: "memory");
        else                  asm volatile("s_waitcnt vmcnt(0)" ::: "memory");
        __builtin_amdgcn_s_barrier();        // all waves' slab-kt loads landed;
                                             // all waves done reading slab kt-1
        __builtin_amdgcn_sched_barrier(0);   // don't hoist ds_read above
        if (kt + 3 < nK) stage(kt + 3, (kt + 3) & 3);

        const u16* Asb = &As[kt & 3][0];
        const u16* Bsb = &Bs[kt & 3][0];
        s16x8 af[2], bf[4];
        #pragma unroll
        for (int i = 0; i < 2; ++i)
            af[i] = *(const s16x8*)&Asb[((lkg) * 64 + wr * 32 + i * 16 + lrow) * 8];
        #pragma unroll
        for (int j = 0; j < 4; ++j)
            bf[j] = *(const s16x8*)&Bsb[((lkg) * 128 + wc * 64 + j * 16 + lrow) * 8];
        #pragma unroll
        for (int i = 0; i < 2; ++i)
            #pragma unroll
            for (int j = 0; j < 4; ++j)
                acc[i][j] = __builtin_amdgcn_mfma_f32_16x16x32_bf16(af[i], bf[j], acc[i][j], 0, 0, 0);
    }

    // epilogue: C/D layout col=lane&15, row=(lane>>4)*4+reg
    float* Cf = (float*)Cv + zb * sCb;
    u16* Ch = (u16*)Cv + zb * sCb;
    const float* Rf = (const float*)residv + zb * sResB;
    const u16* Rh = (const u16*)residv + zb * sResB;
    int col16 = lane & 15;
    int rq = (lane >> 4) * 4;
    #pragma unroll
    for (int j = 0; j < 4; ++j) {
        int n = n0 + wc * 64 + j * 16 + col16;
        float bv = biasb ? biasb[n] : 0.0f;
        #pragma unroll
        for (int i = 0; i < 2; ++i) {
            #pragma unroll
            for (int r = 0; r < 4; ++r) {
                int m = m0 + wr * 32 + i * 16 + rq + r;
                float v = acc[i][j][r] + bv;
                if (act == 1) v = gelu_exact(v);
                if (RES_MODE == 1) v += Rf[(long long)m * ldr + n];
                if (RES_MODE == 2) v += bf2f(Rh[(long long)m * ldr + n]);
                if (OUT_BF16) Ch[(long long)m * ldc + n] = f2bf(v);
                else          Cf[(long long)m * ldc + n] = v;
            }
        }
    }
}

// ---------------------------------------------------------------------------
// Fused flash attention (bf16 I/O): O = softmax(scale * Q K^T [causal]) V.
// QKV bf16 packed [B][T][3*D]; Out bf16 [B][T][D].
// Grid (T/64, B*H), 256 threads = 4 waves, each wave owns 16 query rows.
// ---------------------------------------------------------------------------
__global__ __launch_bounds__(256, 2) void attn_kernel(
    const u16* __restrict__ QKV, u16* __restrict__ Out,
    int causal, float scale)
{
    int qt = blockIdx.x;
    int bh = blockIdx.y;
    int b = bh >> 3;
    int h = bh & 7;
    const u16* Qb = QKV + (long long)b * TT * 3 * DD + (long long)h * HDIM;
    const u16* Kb = Qb + DD;
    const u16* Vb = Qb + 2 * DD;
    u16* Ob = Out + (long long)b * TT * DD + (long long)h * HDIM;

    __shared__ __align__(16) u16 Qs[64 * 104];  // [qrow][d], stride 104
    __shared__ __align__(16) u16 Ks[64 * 104];
    __shared__ __align__(16) u16 Vs[96 * 72];   // [d][krow], stride 72
    __shared__ __align__(16) u16 Ps[64 * 72];   // [qrow][krow]

    int tid = threadIdx.x;
    int wave = tid >> 6;
    int lane = tid & 63;
    int col16 = lane & 15;
    int lkg = lane >> 4;
    int lk = lkg * 8;
    int m0 = qt * 64;

    // ---- stage Q tile 64x96 bf16 (768 x 8-elem slots, 3/thread) ----
    #pragma unroll
    for (int it = 0; it < 3; ++it) {
        int s = tid + it * 256;
        int r = s / 12, c8 = (s % 12) * 8;
        *(s16x8*)&Qs[r * 104 + c8] = *(const s16x8*)(Qb + (long long)(m0 + r) * (3 * DD) + c8);
    }
    __syncthreads();

    s16x8 qf[3];
    #pragma unroll
    for (int kk = 0; kk < 3; ++kk)
        qf[kk] = *(const s16x8*)&Qs[(wave * 16 + col16) * 104 + kk * 32 + lk];

    // ---- QK^T ----
    f32x4 acc[32];
    #pragma unroll
    for (int n = 0; n < 32; ++n) acc[n] = (f32x4){0.f, 0.f, 0.f, 0.f};

    #pragma unroll
    for (int kt = 0; kt < 8; ++kt) {
        #pragma unroll
        for (int it = 0; it < 3; ++it) {
            int s = tid + it * 256;
            int r = s / 12, c8 = (s % 12) * 8;
            *(s16x8*)&Ks[r * 104 + c8] = *(const s16x8*)(Kb + (long long)(kt * 64 + r) * (3 * DD) + c8);
        }
        __syncthreads();
        #pragma unroll
        for (int kk = 0; kk < 3; ++kk) {
            #pragma unroll
            for (int j = 0; j < 4; ++j) {
                s16x8 bfr = *(const s16x8*)&Ks[(j * 16 + col16) * 104 + kk * 32 + lk];
                acc[kt * 4 + j] = __builtin_amdgcn_mfma_f32_16x16x32_bf16(qf[kk], bfr, acc[kt * 4 + j], 0, 0, 0);
            }
        }
        __syncthreads();
    }

    // ---- softmax (registers + shfl only) ----
    int rowbase = m0 + wave * 16 + lkg * 4;
    float mx[4];
    #pragma unroll
    for (int r = 0; r < 4; ++r) mx[r] = -3.0e38f;
    #pragma unroll
    for (int n = 0; n < 32; ++n) {
        int colg = n * 16 + col16;
        #pragma unroll
        for (int r = 0; r < 4; ++r) {
            float v = acc[n][r] * scale;
            if (causal && colg > rowbase + r) v = -3.0e38f;
            acc[n][r] = v;
            mx[r] = fmaxf(mx[r], v);
        }
    }
    #pragma unroll
    for (int m = 1; m <= 8; m <<= 1)
        #pragma unroll
        for (int r = 0; r < 4; ++r)
            mx[r] = fmaxf(mx[r], __shfl_xor(mx[r], m, 64));

    float sum[4] = {0.f, 0.f, 0.f, 0.f};
    #pragma unroll
    for (int n = 0; n < 32; ++n) {
        #pragma unroll
        for (int r = 0; r < 4; ++r) {
            float e = __expf(acc[n][r] - mx[r]);
            acc[n][r] = e;
            sum[r] += e;
        }
    }
    #pragma unroll
    for (int m = 1; m <= 8; m <<= 1)
        #pragma unroll
        for (int r = 0; r < 4; ++r)
            sum[r] += __shfl_xor(sum[r], m, 64);
    float inv[4];
    #pragma unroll
    for (int r = 0; r < 4; ++r) inv[r] = 1.0f / sum[r];

    // ---- PV ----
    f32x4 oacc[6];
    #pragma unroll
    for (int j = 0; j < 6; ++j) oacc[j] = (f32x4){0.f, 0.f, 0.f, 0.f};

    #pragma unroll
    for (int kt = 0; kt < 8; ++kt) {
        __syncthreads();
        // write P strip (unnormalized e, bf16)
        #pragma unroll
        for (int j = 0; j < 4; ++j) {
            #pragma unroll
            for (int r = 0; r < 4; ++r)
                Ps[(wave * 16 + lkg * 4 + r) * 72 + j * 16 + col16] = f2bf(acc[kt * 4 + j][r]);
        }
        // stage V tile transposed: V[kt*64+key][d] -> Vs[d][key]
        #pragma unroll
        for (int it = 0; it < 3; ++it) {
            int s = tid + it * 256;
            int key = s / 12, c8 = (s % 12) * 8;
            s16x8 v = *(const s16x8*)(Vb + (long long)(kt * 64 + key) * (3 * DD) + c8);
            #pragma unroll
            for (int e = 0; e < 8; ++e)
                Vs[(c8 + e) * 72 + key] = (u16)v[e];
        }
        __syncthreads();
        #pragma unroll
        for (int kk = 0; kk < 2; ++kk) {
            s16x8 pf = *(const s16x8*)&Ps[(wave * 16 + col16) * 72 + kk * 32 + lk];
            #pragma unroll
            for (int j = 0; j < 6; ++j) {
                s16x8 vf = *(const s16x8*)&Vs[(j * 16 + col16) * 72 + kk * 32 + lk];
                oacc[j] = __builtin_amdgcn_mfma_f32_16x16x32_bf16(pf, vf, oacc[j], 0, 0, 0);
            }
        }
    }

    // ---- epilogue ----
    int rquad = lkg * 4;
    #pragma unroll
    for (int j = 0; j < 6; ++j) {
        int d = j * 16 + col16;
        #pragma unroll
        for (int r = 0; r < 4; ++r) {
            int row = m0 + wave * 16 + rquad + r;
            Ob[(long long)row * DD + d] = f2bf(oacc[j][r] * inv[r]);
        }
    }
}

// ---------------------------------------------------------------------------
// LayerNorm over last dim (768), bf16 output. One block per row.
// ---------------------------------------------------------------------------
__global__ __launch_bounds__(256) void ln_kernel(
    const float* __restrict__ x, const float* __restrict__ g,
    const float* __restrict__ b, u16* __restrict__ out)
{
    long long row = blockIdx.x;
    const float* xr = x + row * DD;
    u16* orow = out + row * DD;
    int t = threadIdx.x;
    float vals[3];
    float s = 0.f, ss = 0.f;
    #pragma unroll
    for (int i = 0; i < 3; i++) {
        float v = xr[t + i * 256];
        vals[i] = v; s += v; ss += v * v;
    }
    __shared__ float rs[256], rss[256];
    rs[t] = s; rss[t] = ss; __syncthreads();
    for (int k = 128; k > 0; k >>= 1) {
        if (t < k) { rs[t] += rs[t + k]; rss[t] += rss[t + k]; }
        __syncthreads();
    }
    float mean = rs[0] * (1.0f / DD);
    float var = rss[0] * (1.0f / DD) - mean * mean;
    float inv = rsqrtf(var + 1e-5f);
    #pragma unroll
    for (int i = 0; i < 3; i++) {
        int d = t + i * 256;
        orow[d] = f2bf((vals[i] - mean) * inv * g[d] + b[d]);
    }
}

// ---------------------------------------------------------------------------
// Router part 1: partial column sums of x over T.
// ---------------------------------------------------------------------------
__global__ __launch_bounds__(256) void mean_part_kernel(
    const float* __restrict__ x, float* __restrict__ part)
{
    int b = blockIdx.x, dseg = blockIdx.y, rc = blockIdx.z;
    int d = dseg * 256 + threadIdx.x;
    const float* xb = x + (long long)b * TT * DD;
    float s = 0.f;
    int r0 = rc * 64;
    for (int r = r0; r < r0 + 64; ++r) s += xb[(long long)r * DD + d];
    part[((long long)b * 8 + rc) * DD + d] = s;
}

// ---------------------------------------------------------------------------
// Router part 2.
// ---------------------------------------------------------------------------
__global__ __launch_bounds__(128) void router_kernel(
    const float* __restrict__ part, const float* __restrict__ w1,
    const float* __restrict__ b1, const float* __restrict__ w2,
    const float* __restrict__ b2, int* __restrict__ idx)
{
    int b = blockIdx.x, t = threadIdx.x;
    __shared__ float xm[DD];
    __shared__ float h[128];
    __shared__ float logits[8];
    for (int i = t; i < DD; i += 128) {
        float s = 0.f;
        for (int rc = 0; rc < 8; ++rc) s += part[((long long)b * 8 + rc) * DD + i];
        xm[i] = s * (1.0f / TT);
    }
    __syncthreads();
    {
        float s = b1[t];
        const float* w = w1 + (long long)t * DD;
        for (int d = 0; d < DD; ++d) s += xm[d] * w[d];
        h[t] = gelu_exact(s);
    }
    __syncthreads();
    if (t < 8) {
        float s = b2[t];
        const float* w = w2 + t * 128;
        for (int d = 0; d < 128; ++d) s += h[d] * w[d];
        logits[t] = s;
    }
    __syncthreads();
    if (t == 0) {
        int bsix = 0;
        for (int i = 1; i < 4; i++) if (logits[i] > logits[bsix]) bsix = i;
        int btix = 4;
        for (int i = 5; i < 8; i++) if (logits[i] > logits[btix]) btix = i;
        idx[b] = bsix;
        idx[b + BB] = btix - 4;
    }
}

// ---------------------------------------------------------------------------
static void run_gemm2(hipStream_t stream,
    const u16* A, long long sAb, int lda,
    const u16* B, const int* bidx, long long sBexp, int ldb,
    void* C, long long sCb, int ldc,
    const float* bias, long long sBiasExp,
    const void* resid, long long sResB, int ldr,
    int act, int N, int K, int outbf, int resmode)
{
    dim3 grid(N / 128, 8, BB);
    if (outbf && resmode == 0)
        gemm_bf16_kernel<1, 0><<<grid, 256, 0, stream>>>(A, sAb, lda, B, bidx, sBexp, ldb,
            C, sCb, ldc, bias, sBiasExp, resid, sResB, ldr, act, N, K);
    else if (outbf)
        gemm_bf16_kernel<1, 2><<<grid, 256, 0, stream>>>(A, sAb, lda, B, bidx, sBexp, ldb,
            C, sCb, ldc, bias, sBiasExp, resid, sResB, ldr, act, N, K);
    else
        gemm_bf16_kernel<0, 1><<<grid, 256, 0, stream>>>(A, sAb, lda, B, bidx, sBexp, ldb,
            C, sCb, ldc, bias, sBiasExp, resid, sResB, ldr, act, N, K);
}

extern "C" void kernel_launch(void* const* d_in, const int* in_sizes, int n_in,
                              void* d_out, int out_size, void* d_ws, size_t ws_size,
                              hipStream_t stream)
{
    const float* x       = (const float*)d_in[0];
    const float* rw1     = (const float*)d_in[1];
    const float* rb1     = (const float*)d_in[2];
    const float* rw2     = (const float*)d_in[3];
    const float* rb2     = (const float*)d_in[4];
    const float* gs      = (const float*)d_in[5];
    const float* bs      = (const float*)d_in[6];
    const float* gt      = (const float*)d_in[7];
    const float* btt     = (const float*)d_in[8];
    const float* gm      = (const float*)d_in[9];
    const float* bm      = (const float*)d_in[10];
    const float* sp_wqkv = (const float*)d_in[11];
    const float* sp_bqkv = (const float*)d_in[12];
    const float* sp_wo   = (const float*)d_in[13];
    const float* sp_bo   = (const float*)d_in[14];
    const float* tp_wq   = (const float*)d_in[15];
    const float* tp_bq   = (const float*)d_in[16];
    const float* tp_wk   = (const float*)d_in[17];
    const float* tp_bk   = (const float*)d_in[18];
    const float* tp_wv   = (const float*)d_in[19];
    const float* tp_bv   = (const float*)d_in[20];
    const float* tp_wo   = (const float*)d_in[21];
    const float* tp_bo   = (const float*)d_in[22];
    const float* c_wqkv  = (const float*)d_in[23];
    const float* c_bqkv  = (const float*)d_in[24];
    const float* c_wo    = (const float*)d_in[25];
    const float* c_bo    = (const float*)d_in[26];
    const float* m_w1    = (const float*)d_in[27];
    const float* m_b1    = (const float*)d_in[28];
    const float* m_w2    = (const float*)d_in[29];
    const float* m_b2    = (const float*)d_in[30];
    float* out = (float*)d_out;

    float* ws = (float*)d_ws;
    size_t o = 0;
    float* part  = ws + o; o += (size_t)BB * 8 * DD;
    int*   idx   = (int*)(ws + o); o += 16;
    float* tpb   = ws + o; o += 4 * 2304;                     // packed temporal bias
    float* x1b   = ws + o; o += (size_t)4096 * DD;            // f32 (x + fused)
    u16* xnb   = (u16*)(ws + o); o += (size_t)4096 * DD / 2;  // LN out (bf16)
    u16* tmp1b = (u16*)(ws + o); o += (size_t)4096 * DD / 2;  // attention out
    u16* tmp2b = (u16*)(ws + o); o += (size_t)4096 * DD / 2;  // LN for mlp
    u16* soutb = (u16*)(ws + o); o += (size_t)4096 * DD / 2;  // spatial_out
    u16* toutb = (u16*)(ws + o); o += (size_t)4096 * DD / 2;  // temporal_out
    u16* qkvb  = (u16*)(ws + o); o += (size_t)4096 * 2304 / 2;// q|k|v packed bf16
    u16* yb    = (u16*)(ws + o); o += (size_t)4096 * 3072 / 2;// mlp hidden bf16
    u16* wpool = (u16*)(ws + o); o += (size_t)CUM10 / 2;      // bf16 weights

    u16* w_sp_qkv = wpool;
    u16* w_sp_wo  = wpool + CUM1;
    u16* w_tp_qkv = wpool + CUM2;   // interleaved [e][3*DD][DD]
    u16* w_tp_o   = wpool + CUM5;
    u16* w_c_qkv  = wpool + CUM6;
    u16* w_c_wo   = wpool + CUM7;
    u16* w_m1     = wpool + CUM8;
    u16* w_m2     = wpool + CUM9;

    int* idx_s = idx;
    int* idx_t = idx + BB;

    const long long sTD  = (long long)TT * DD;       // 512*768
    const long long sT3D = (long long)TT * 3 * DD;   // 512*2304
    const long long sT4D = (long long)TT * 4 * DD;   // 512*3072
    const float qk_scale = 1.0f / sqrtf((float)HDIM);

    // ---- weight convert (f32 -> bf16) + temporal bias pack ----
    cvt_kernel<<<(int)((CUM10 / 8 + 255) / 256), 256, 0, stream>>>(
        sp_wqkv, sp_wo, tp_wq, tp_wk, tp_wv, tp_wo, c_wqkv, c_wo, m_w1, m_w2, wpool);
    pack_tpb_kernel<<<36, 256, 0, stream>>>(tp_bq, tp_bk, tp_bv, tpb);

    // ---- router ----
    mean_part_kernel<<<dim3(BB, 3, 8), 256, 0, stream>>>(x, part);
    router_kernel<<<BB, 128, 0, stream>>>(part, rw1, rb1, rw2, rb2, idx);

    // ---- spatial branch ----
    ln_kernel<<<4096, 256, 0, stream>>>(x, gs, bs, xnb);
    // qkv = xn @ sp_wqkv[idx_s]^T + sp_bqkv[idx_s]
    run_gemm2(stream, xnb, sTD, DD, w_sp_qkv, idx_s, 3 * DDDD, DD,
              qkvb, sT3D, 3 * DD, sp_bqkv, 3 * DD, nullptr, 0, 0,
              0, 3 * DD, DD, 1, 0);
    attn_kernel<<<dim3(TT / 64, BB * HH), 256, 0, stream>>>(qkvb, tmp1b, 0, qk_scale);
    // spatial_out = O @ sp_wo[idx_s]^T + sp_bo[idx_s]
    run_gemm2(stream, tmp1b, sTD, DD, w_sp_wo, idx_s, DDDD, DD,
              soutb, sTD, DD, sp_bo, DD, nullptr, 0, 0,
              0, DD, DD, 1, 0);

    // ---- temporal branch ----
    ln_kernel<<<4096, 256, 0, stream>>>(x, gt, btt, xnb);
    // q|k|v = xt @ tp_wqkv[idx_t]^T + tpb[idx_t]   (single merged GEMM)
    run_gemm2(stream, xnb, sTD, DD, w_tp_qkv, idx_t, 3 * DDDD, DD,
              qkvb, sT3D, 3 * DD, tpb, 3 * DD, nullptr, 0, 0,
              0, 3 * DD, DD, 1, 0);
    attn_kernel<<<dim3(TT / 64, BB * HH), 256, 0, stream>>>(qkvb, tmp1b, 1, qk_scale);
    // temporal_out = xt + O @ tp_wo[idx_t]^T + tp_bo[idx_t]   (bf16 resid xnb)
    run_gemm2(stream, tmp1b, sTD, DD, w_tp_o, idx_t, DDDD, DD,
              toutb, sTD, DD, tp_bo, DD, xnb, sTD, DD,
              0, DD, DD, 1, 2);

    // ---- cross attention ----
    run_gemm2(stream, soutb, sTD, DD, w_c_qkv, nullptr, 0, DD,
              qkvb, sT3D, 3 * DD, c_bqkv, 0, nullptr, 0, 0,
              0, DD, DD, 1, 0);
    run_gemm2(stream, toutb, sTD, DD, w_c_qkv + DDDD, nullptr, 0, DD,
              qkvb + DD, sT3D, 3 * DD, c_bqkv + DD, 0, nullptr, 0, 0,
              0, 2 * DD, DD, 1, 0);
    attn_kernel<<<dim3(TT / 64, BB * HH), 256, 0, stream>>>(qkvb, tmp1b, 0, qk_scale);
    // x1 = x + (fused_attn @ cross_wo^T + cross_bo)   (f32 out, f32 resid)
    run_gemm2(stream, tmp1b, sTD, DD, w_c_wo, nullptr, 0, DD,
              x1b, sTD, DD, c_bo, 0, x, sTD, DD,
              0, DD, DD, 0, 1);

    // ---- MLP ----
    ln_kernel<<<4096, 256, 0, stream>>>(x1b, gm, bm, tmp2b);
    // y = gelu(ln @ mlp_w1^T + b1) -> bf16
    run_gemm2(stream, tmp2b, sTD, DD, w_m1, nullptr, 0, DD,
              yb, sT4D, 4 * DD, m_b1, 0, nullptr, 0, 0,
              1, 4 * DD, DD, 1, 0);
    // out = x1 + y @ mlp_w2^T + b2   (f32 out, f32 resid)
    run_gemm2(stream, yb, sT4D, 4 * DD, w_m2, nullptr, 0, 4 * DD,
              out, sTD, DD, m_b2, 0, x1b, sTD, DD,
              0, DD, 4 * DD, 0, 1);
}

// Round 6
// 694.379 us; speedup vs baseline: 1.9241x; 1.1433x over previous
//
#include <hip/hip_runtime.h>
#include <math.h>

// Problem constants
#define BB 8
#define TT 512
#define DD 768
#define HH 8
#define HDIM 96
#define DDDD 589824LL   // 768*768

typedef short s16x8 __attribute__((ext_vector_type(8)));
typedef float f32x4 __attribute__((ext_vector_type(4)));
typedef unsigned short u16;

__device__ inline unsigned short f2bf(float f) {
    union { float f; unsigned u; } v; v.f = f;
    unsigned u = v.u;
    unsigned r = (u + 0x7fffu + ((u >> 16) & 1u)) >> 16;
    return (unsigned short)r;
}

__device__ inline float bf2f(u16 h) {
    union { unsigned u; float f; } v; v.u = ((unsigned)h) << 16; return v.f;
}

__device__ inline float gelu_exact(float x) {
    return 0.5f * x * (1.0f + erff(x * 0.70710678118654752440f));
}

__device__ __forceinline__ void gload16(const void* g, void* l) {
    __builtin_amdgcn_global_load_lds(
        (const __attribute__((address_space(1))) unsigned int*)g,
        (__attribute__((address_space(3))) unsigned int*)l,
        16, 0, 0);
}

// Tiled activation index: 64-row tiles, k-major windows of 8.
// elem (m, k) of a [M][ldn] matrix -> ((m/64)*(ldn/8) + k/8)*512 + (m%64)*8 + k%8
__device__ __forceinline__ long long tix(int m, int k, int ldn) {
    return ((long long)(m >> 6) * (ldn >> 3) + (k >> 3)) * 512 + ((m & 63) << 3) + (k & 7);
}

// ---------------------------------------------------------------------------
// Weight convert: f32 -> bf16, written in k-major TILED layout
//   B'[ntile128][kw=K/8][row128][8]  (per matrix; experts consecutive).
// tp_wq/wk/wv are interleaved into one [2304][768] matrix per expert.
// A BK=32 slab of a 128-col block is then one contiguous 8 KB run ->
// global_load_lds staging is perfectly coalesced (16 lines/wave instr).
// ---------------------------------------------------------------------------
#define CUM1  7077888LL
#define CUM2  9437184LL
#define CUM3  11796480LL
#define CUM4  14155776LL
#define CUM5  16515072LL
#define CUM6  18874368LL
#define CUM7  20643840LL
#define CUM8  21233664LL
#define CUM9  23592960LL
#define CUM10 25952256LL

__global__ __launch_bounds__(256) void cvt_kernel(
    const float* __restrict__ s0, const float* __restrict__ s1,
    const float* __restrict__ s2, const float* __restrict__ s3,
    const float* __restrict__ s4, const float* __restrict__ s5,
    const float* __restrict__ s6, const float* __restrict__ s7,
    const float* __restrict__ s8, const float* __restrict__ s9,
    u16* __restrict__ dpool)
{
    long long g = ((long long)blockIdx.x * 256 + threadIdx.x) * 8;
    if (g >= CUM10) return;
    const float* s; long long i, base; int n, k, K = 768;
    const long long SZQKV = 2304LL * 768;
    if (g < CUM1) {                 // sp_wqkv: 4 x [2304][768]
        s = s0; i = g;
        long long e = i / SZQKV, r = i - e * SZQKV;
        n = (int)(r / 768); k = (int)(r % 768); base = e * 3 * DDDD;
    } else if (g < CUM2) {          // sp_wo: 4 x [768][768]
        s = s1; i = g - CUM1;
        long long e = i / DDDD, r = i - e * DDDD;
        n = (int)(r / 768); k = (int)(r % 768); base = CUM1 + e * DDDD;
    } else if (g < CUM5) {          // tp_wq/wk/wv -> interleaved [2304][768]
        int tp = (g < CUM3) ? 0 : (g < CUM4) ? 1 : 2;
        s = (tp == 0) ? s2 : (tp == 1) ? s3 : s4;
        i = g - ((tp == 0) ? CUM2 : (tp == 1) ? CUM3 : CUM4);
        long long e = i / DDDD, r = i - e * DDDD;
        n = tp * 768 + (int)(r / 768); k = (int)(r % 768);
        base = CUM2 + e * 3 * DDDD;
    } else if (g < CUM6) {          // tp_wo: 4 x [768][768]
        s = s5; i = g - CUM5;
        long long e = i / DDDD, r = i - e * DDDD;
        n = (int)(r / 768); k = (int)(r % 768); base = CUM5 + e * DDDD;
    } else if (g < CUM7) {          // c_wqkv: [2304][768]
        s = s6; i = g - CUM6;
        n = (int)(i / 768); k = (int)(i % 768); base = CUM6;
    } else if (g < CUM8) {          // c_wo: [768][768]
        s = s7; i = g - CUM7;
        n = (int)(i / 768); k = (int)(i % 768); base = CUM7;
    } else if (g < CUM9) {          // m_w1: [3072][768]
        s = s8; i = g - CUM8;
        n = (int)(i / 768); k = (int)(i % 768); base = CUM8;
    } else {                        // m_w2: [768][3072]
        s = s9; i = g - CUM9;
        n = (int)(i / 3072); k = (int)(i % 3072); base = CUM9; K = 3072;
    }
    float4 a = *(const float4*)(s + i);
    float4 b = *(const float4*)(s + i + 4);
    s16x8 o;
    o[0] = f2bf(a.x); o[1] = f2bf(a.y); o[2] = f2bf(a.z); o[3] = f2bf(a.w);
    o[4] = f2bf(b.x); o[5] = f2bf(b.y); o[6] = f2bf(b.z); o[7] = f2bf(b.w);
    long long d = base + (((long long)(n >> 7) * (K >> 3) + (k >> 3)) << 10) + ((n & 127) << 3);
    *(s16x8*)(dpool + d) = o;
}

// pack temporal biases [4][2304] = bq|bk|bv
__global__ __launch_bounds__(256) void pack_tpb_kernel(
    const float* __restrict__ bq, const float* __restrict__ bk,
    const float* __restrict__ bv, float* __restrict__ dst)
{
    int t = blockIdx.x * 256 + threadIdx.x;
    if (t >= 4 * 2304) return;
    int e = t / 2304, n = t - e * 2304;
    float v = (n < 768) ? bq[e * 768 + n]
            : (n < 1536) ? bk[e * 768 + n - 768]
            : bv[e * 768 + n - 1536];
    dst[t] = v;
}

// ---------------------------------------------------------------------------
// bf16 GEMM: C[z] = A[z] * B^T (+bias) (gelu?) (+resid)
//   A TILED [mtile64][kw][64][8] per batch; B TILED [ntile128][kw][128][8].
//   Tile 64x128 (MxN), BK=32, 4 waves each 32x64 via 2x4 MFMA 16x16x32.
//   4-slab ring pipeline depth 3 with counted vmcnt (never 0 in-loop).
//   Staging: 3 x gload16/thread, global sources CONTIGUOUS per slab ->
//   perfectly coalesced (1 KB/wave-instr), LDS dests linear, ds_read
//   conflict-free.  LDS 48 KB -> 3 blocks/CU.
//   OUT_MODE: 0 f32 row-major, 1 bf16 row-major, 2 bf16 tiled.
//   RES_MODE: 0 none, 1 f32 row-major, 2 bf16 tiled.
//   Requires M=512, N%128==0, K%32==0, K/32 >= 4.
// ---------------------------------------------------------------------------
#define SLABA 2048    // 64*32 elems = 4 KB
#define SLABB 4096    // 128*32 elems = 8 KB

template<int OUT_MODE, int RES_MODE>
__global__ __launch_bounds__(256) void gemm_bf16_kernel(
    const u16* __restrict__ A, long long sAb,
    const u16* __restrict__ B, const int* __restrict__ bidx, long long sBexp,
    void* __restrict__ Cv, long long sCb, int ldc,
    const float* __restrict__ bias, long long sBiasExp,
    const void* __restrict__ residv, long long sResB, int ldr,
    int act, int N, int K)
{
    int zb = blockIdx.z;
    int kw8 = K >> 3;
    const u16* Ab = A + zb * sAb + (long long)blockIdx.y * kw8 * 512;
    const u16* Bb = B + (bidx ? (long long)bidx[zb] * sBexp : 0)
                      + (long long)blockIdx.x * kw8 * 1024;
    const float* biasb = bias ? (bias + (bidx ? (long long)bidx[zb] * sBiasExp : 0)) : nullptr;

    __shared__ __align__(16) u16 As[4][SLABA];   // 16 KB
    __shared__ __align__(16) u16 Bs[4][SLABB];   // 32 KB

    int tid = threadIdx.x;
    int wave = tid >> 6, lane = tid & 63;
    int wr = wave >> 1, wc = wave & 1;
    int lrow = lane & 15, lkg = lane >> 4;

    f32x4 acc[2][4];
    #pragma unroll
    for (int i = 0; i < 2; i++)
        #pragma unroll
        for (int j = 0; j < 4; j++)
            acc[i][j] = (f32x4){0.f, 0.f, 0.f, 0.f};

    const u16* agt = Ab + tid * 8;
    const u16* bgt = Bb + tid * 8;
    u16* al  = (u16*)As + tid * 8;
    u16* bl0 = (u16*)Bs + tid * 8;
    u16* bl1 = (u16*)Bs + (tid + 256) * 8;

    auto stage = [&](int slab, int buf) {
        gload16(agt + slab * SLABA,        al  + buf * SLABA);
        gload16(bgt + slab * SLABB,        bl0 + buf * SLABB);
        gload16(bgt + slab * SLABB + 2048, bl1 + buf * SLABB);
    };

    int nK = K >> 5;
    stage(0, 0);
    stage(1, 1);
    stage(2, 2);

    for (int kt = 0; kt < nK; ++kt) {
        if (kt + 2 < nK)      asm volatile("s_waitcnt vmcnt(6)" ::: "memory");
        else if (kt + 1 < nK) asm volatile("s_waitcnt vmcnt(3)" ::: "memory");
        else                  asm volatile("s_waitcnt vmcnt(0)" ::: "memory");
        __builtin_amdgcn_s_barrier();        // all waves' slab-kt loads landed;
                                             // all waves done reading slab kt-1
        __builtin_amdgcn_sched_barrier(0);
        if (kt + 3 < nK) stage(kt + 3, (kt + 3) & 3);

        const u16* Asb = &As[kt & 3][0];
        const u16* Bsb = &Bs[kt & 3][0];
        s16x8 af[2], bf[4];
        #pragma unroll
        for (int i = 0; i < 2; ++i)
            af[i] = *(const s16x8*)&Asb[((lkg) * 64 + wr * 32 + i * 16 + lrow) * 8];
        #pragma unroll
        for (int j = 0; j < 4; ++j)
            bf[j] = *(const s16x8*)&Bsb[((lkg) * 128 + wc * 64 + j * 16 + lrow) * 8];
        #pragma unroll
        for (int i = 0; i < 2; ++i)
            #pragma unroll
            for (int j = 0; j < 4; ++j)
                acc[i][j] = __builtin_amdgcn_mfma_f32_16x16x32_bf16(af[i], bf[j], acc[i][j], 0, 0, 0);
    }

    // epilogue: C/D layout col=lane&15, row=(lane>>4)*4+reg
    int n0 = blockIdx.x * 128;
    int m0 = blockIdx.y * 64;
    float* Cf = (float*)Cv + zb * sCb;
    u16* Ch = (u16*)Cv + zb * sCb;
    const float* Rf = (const float*)residv + zb * sResB;
    const u16* Rh = (const u16*)residv + zb * sResB;
    int col16 = lane & 15;
    int rq = (lane >> 4) * 4;
    #pragma unroll
    for (int j = 0; j < 4; ++j) {
        int n = n0 + wc * 64 + j * 16 + col16;
        float bv = biasb ? biasb[n] : 0.0f;
        #pragma unroll
        for (int i = 0; i < 2; ++i) {
            #pragma unroll
            for (int r = 0; r < 4; ++r) {
                int m = m0 + wr * 32 + i * 16 + rq + r;
                float v = acc[i][j][r] + bv;
                if (act == 1) v = gelu_exact(v);
                if (RES_MODE == 1) v += Rf[(long long)m * ldr + n];
                if (RES_MODE == 2) v += bf2f(Rh[tix(m, n, ldr)]);
                if (OUT_MODE == 0) Cf[(long long)m * ldc + n] = v;
                if (OUT_MODE == 1) Ch[(long long)m * ldc + n] = f2bf(v);
                if (OUT_MODE == 2) Ch[tix(m, n, ldc)] = f2bf(v);
            }
        }
    }
}

// ---------------------------------------------------------------------------
// Fused flash attention (bf16): O = softmax(scale * Q K^T [causal]) V.
// QKV bf16 ROW-MAJOR [B][T][3*D]; Out bf16 TILED (A-layout for next GEMM).
// Grid (T/64, B*H), 256 threads = 4 waves, each wave owns 16 query rows.
// ---------------------------------------------------------------------------
__global__ __launch_bounds__(256, 2) void attn_kernel(
    const u16* __restrict__ QKV, u16* __restrict__ Out,
    int causal, float scale)
{
    int qt = blockIdx.x;
    int bh = blockIdx.y;
    int b = bh >> 3;
    int h = bh & 7;
    const u16* Qb = QKV + (long long)b * TT * 3 * DD + (long long)h * HDIM;
    const u16* Kb = Qb + DD;
    const u16* Vb = Qb + 2 * DD;
    u16* Ob = Out + (long long)b * TT * DD;   // tiled within batch

    __shared__ __align__(16) u16 Qs[64 * 104];  // [qrow][d], stride 104
    __shared__ __align__(16) u16 Ks[64 * 104];
    __shared__ __align__(16) u16 Vs[96 * 72];   // [d][krow], stride 72
    __shared__ __align__(16) u16 Ps[64 * 72];   // [qrow][krow]

    int tid = threadIdx.x;
    int wave = tid >> 6;
    int lane = tid & 63;
    int col16 = lane & 15;
    int lkg = lane >> 4;
    int lk = lkg * 8;
    int m0 = qt * 64;

    // ---- stage Q tile 64x96 bf16 ----
    #pragma unroll
    for (int it = 0; it < 3; ++it) {
        int s = tid + it * 256;
        int r = s / 12, c8 = (s % 12) * 8;
        *(s16x8*)&Qs[r * 104 + c8] = *(const s16x8*)(Qb + (long long)(m0 + r) * (3 * DD) + c8);
    }
    __syncthreads();

    s16x8 qf[3];
    #pragma unroll
    for (int kk = 0; kk < 3; ++kk)
        qf[kk] = *(const s16x8*)&Qs[(wave * 16 + col16) * 104 + kk * 32 + lk];

    // ---- QK^T ----
    f32x4 acc[32];
    #pragma unroll
    for (int n = 0; n < 32; ++n) acc[n] = (f32x4){0.f, 0.f, 0.f, 0.f};

    #pragma unroll
    for (int kt = 0; kt < 8; ++kt) {
        #pragma unroll
        for (int it = 0; it < 3; ++it) {
            int s = tid + it * 256;
            int r = s / 12, c8 = (s % 12) * 8;
            *(s16x8*)&Ks[r * 104 + c8] = *(const s16x8*)(Kb + (long long)(kt * 64 + r) * (3 * DD) + c8);
        }
        __syncthreads();
        #pragma unroll
        for (int kk = 0; kk < 3; ++kk) {
            #pragma unroll
            for (int j = 0; j < 4; ++j) {
                s16x8 bfr = *(const s16x8*)&Ks[(j * 16 + col16) * 104 + kk * 32 + lk];
                acc[kt * 4 + j] = __builtin_amdgcn_mfma_f32_16x16x32_bf16(qf[kk], bfr, acc[kt * 4 + j], 0, 0, 0);
            }
        }
        __syncthreads();
    }

    // ---- softmax (registers + shfl only) ----
    int rowbase = m0 + wave * 16 + lkg * 4;
    float mx[4];
    #pragma unroll
    for (int r = 0; r < 4; ++r) mx[r] = -3.0e38f;
    #pragma unroll
    for (int n = 0; n < 32; ++n) {
        int colg = n * 16 + col16;
        #pragma unroll
        for (int r = 0; r < 4; ++r) {
            float v = acc[n][r] * scale;
            if (causal && colg > rowbase + r) v = -3.0e38f;
            acc[n][r] = v;
            mx[r] = fmaxf(mx[r], v);
        }
    }
    #pragma unroll
    for (int m = 1; m <= 8; m <<= 1)
        #pragma unroll
        for (int r = 0; r < 4; ++r)
            mx[r] = fmaxf(mx[r], __shfl_xor(mx[r], m, 64));

    float sum[4] = {0.f, 0.f, 0.f, 0.f};
    #pragma unroll
    for (int n = 0; n < 32; ++n) {
        #pragma unroll
        for (int r = 0; r < 4; ++r) {
            float e = __expf(acc[n][r] - mx[r]);
            acc[n][r] = e;
            sum[r] += e;
        }
    }
    #pragma unroll
    for (int m = 1; m <= 8; m <<= 1)
        #pragma unroll
        for (int r = 0; r < 4; ++r)
            sum[r] += __shfl_xor(sum[r], m, 64);
    float inv[4];
    #pragma unroll
    for (int r = 0; r < 4; ++r) inv[r] = 1.0f / sum[r];

    // ---- PV ----
    f32x4 oacc[6];
    #pragma unroll
    for (int j = 0; j < 6; ++j) oacc[j] = (f32x4){0.f, 0.f, 0.f, 0.f};

    #pragma unroll
    for (int kt = 0; kt < 8; ++kt) {
        __syncthreads();
        #pragma unroll
        for (int j = 0; j < 4; ++j) {
            #pragma unroll
            for (int r = 0; r < 4; ++r)
                Ps[(wave * 16 + lkg * 4 + r) * 72 + j * 16 + col16] = f2bf(acc[kt * 4 + j][r]);
        }
        #pragma unroll
        for (int it = 0; it < 3; ++it) {
            int s = tid + it * 256;
            int key = s / 12, c8 = (s % 12) * 8;
            s16x8 v = *(const s16x8*)(Vb + (long long)(kt * 64 + key) * (3 * DD) + c8);
            #pragma unroll
            for (int e = 0; e < 8; ++e)
                Vs[(c8 + e) * 72 + key] = (u16)v[e];
        }
        __syncthreads();
        #pragma unroll
        for (int kk = 0; kk < 2; ++kk) {
            s16x8 pf = *(const s16x8*)&Ps[(wave * 16 + col16) * 72 + kk * 32 + lk];
            #pragma unroll
            for (int j = 0; j < 6; ++j) {
                s16x8 vf = *(const s16x8*)&Vs[(j * 16 + col16) * 72 + kk * 32 + lk];
                oacc[j] = __builtin_amdgcn_mfma_f32_16x16x32_bf16(pf, vf, oacc[j], 0, 0, 0);
            }
        }
    }

    // ---- epilogue: write TILED ----
    int rquad = lkg * 4;
    #pragma unroll
    for (int j = 0; j < 6; ++j) {
        int d = h * 96 + j * 16 + col16;
        #pragma unroll
        for (int r = 0; r < 4; ++r) {
            int row = m0 + wave * 16 + rquad + r;
            Ob[tix(row, d, DD)] = f2bf(oacc[j][r] * inv[r]);
        }
    }
}

// ---------------------------------------------------------------------------
// LayerNorm over last dim (768), bf16 TILED output. One block per row.
// ---------------------------------------------------------------------------
__global__ __launch_bounds__(256) void ln_kernel(
    const float* __restrict__ x, const float* __restrict__ g,
    const float* __restrict__ b, u16* __restrict__ out)
{
    long long row = blockIdx.x;
    const float* xr = x + row * DD;
    u16* ob = out + (row >> 9) * ((long long)TT * DD);  // batch base
    int m = (int)(row & 511);
    int t = threadIdx.x;
    float vals[3];
    float s = 0.f, ss = 0.f;
    #pragma unroll
    for (int i = 0; i < 3; i++) {
        float v = xr[t + i * 256];
        vals[i] = v; s += v; ss += v * v;
    }
    __shared__ float rs[256], rss[256];
    rs[t] = s; rss[t] = ss; __syncthreads();
    for (int k = 128; k > 0; k >>= 1) {
        if (t < k) { rs[t] += rs[t + k]; rss[t] += rss[t + k]; }
        __syncthreads();
    }
    float mean = rs[0] * (1.0f / DD);
    float var = rss[0] * (1.0f / DD) - mean * mean;
    float inv = rsqrtf(var + 1e-5f);
    #pragma unroll
    for (int i = 0; i < 3; i++) {
        int d = t + i * 256;
        ob[tix(m, d, DD)] = f2bf((vals[i] - mean) * inv * g[d] + b[d]);
    }
}

// ---------------------------------------------------------------------------
// Router part 1: partial column sums of x over T.
// ---------------------------------------------------------------------------
__global__ __launch_bounds__(256) void mean_part_kernel(
    const float* __restrict__ x, float* __restrict__ part)
{
    int b = blockIdx.x, dseg = blockIdx.y, rc = blockIdx.z;
    int d = dseg * 256 + threadIdx.x;
    const float* xb = x + (long long)b * TT * DD;
    float s = 0.f;
    int r0 = rc * 64;
    for (int r = r0; r < r0 + 64; ++r) s += xb[(long long)r * DD + d];
    part[((long long)b * 8 + rc) * DD + d] = s;
}

// ---------------------------------------------------------------------------
// Router part 2.
// ---------------------------------------------------------------------------
__global__ __launch_bounds__(128) void router_kernel(
    const float* __restrict__ part, const float* __restrict__ w1,
    const float* __restrict__ b1, const float* __restrict__ w2,
    const float* __restrict__ b2, int* __restrict__ idx)
{
    int b = blockIdx.x, t = threadIdx.x;
    __shared__ float xm[DD];
    __shared__ float h[128];
    __shared__ float logits[8];
    for (int i = t; i < DD; i += 128) {
        float s = 0.f;
        for (int rc = 0; rc < 8; ++rc) s += part[((long long)b * 8 + rc) * DD + i];
        xm[i] = s * (1.0f / TT);
    }
    __syncthreads();
    {
        float s = b1[t];
        const float* w = w1 + (long long)t * DD;
        for (int d = 0; d < DD; ++d) s += xm[d] * w[d];
        h[t] = gelu_exact(s);
    }
    __syncthreads();
    if (t < 8) {
        float s = b2[t];
        const float* w = w2 + t * 128;
        for (int d = 0; d < 128; ++d) s += h[d] * w[d];
        logits[t] = s;
    }
    __syncthreads();
    if (t == 0) {
        int bsix = 0;
        for (int i = 1; i < 4; i++) if (logits[i] > logits[bsix]) bsix = i;
        int btix = 4;
        for (int i = 5; i < 8; i++) if (logits[i] > logits[btix]) btix = i;
        idx[b] = bsix;
        idx[b + BB] = btix - 4;
    }
}

// ---------------------------------------------------------------------------
static void run_gemm2(hipStream_t stream,
    const u16* A, long long sAb,
    const u16* B, const int* bidx, long long sBexp,
    void* C, long long sCb, int ldc,
    const float* bias, long long sBiasExp,
    const void* resid, long long sResB, int ldr,
    int act, int N, int K, int outmode, int resmode)
{
    dim3 grid(N / 128, 8, BB);
    if (outmode == 1)
        gemm_bf16_kernel<1, 0><<<grid, 256, 0, stream>>>(A, sAb, B, bidx, sBexp,
            C, sCb, ldc, bias, sBiasExp, resid, sResB, ldr, act, N, K);
    else if (outmode == 2 && resmode == 0)
        gemm_bf16_kernel<2, 0><<<grid, 256, 0, stream>>>(A, sAb, B, bidx, sBexp,
            C, sCb, ldc, bias, sBiasExp, resid, sResB, ldr, act, N, K);
    else if (outmode == 2)
        gemm_bf16_kernel<2, 2><<<grid, 256, 0, stream>>>(A, sAb, B, bidx, sBexp,
            C, sCb, ldc, bias, sBiasExp, resid, sResB, ldr, act, N, K);
    else
        gemm_bf16_kernel<0, 1><<<grid, 256, 0, stream>>>(A, sAb, B, bidx, sBexp,
            C, sCb, ldc, bias, sBiasExp, resid, sResB, ldr, act, N, K);
}

extern "C" void kernel_launch(void* const* d_in, const int* in_sizes, int n_in,
                              void* d_out, int out_size, void* d_ws, size_t ws_size,
                              hipStream_t stream)
{
    const float* x       = (const float*)d_in[0];
    const float* rw1     = (const float*)d_in[1];
    const float* rb1     = (const float*)d_in[2];
    const float* rw2     = (const float*)d_in[3];
    const float* rb2     = (const float*)d_in[4];
    const float* gs      = (const float*)d_in[5];
    const float* bs      = (const float*)d_in[6];
    const float* gt      = (const float*)d_in[7];
    const float* btt     = (const float*)d_in[8];
    const float* gm      = (const float*)d_in[9];
    const float* bm      = (const float*)d_in[10];
    const float* sp_wqkv = (const float*)d_in[11];
    const float* sp_bqkv = (const float*)d_in[12];
    const float* sp_wo   = (const float*)d_in[13];
    const float* sp_bo   = (const float*)d_in[14];
    const float* tp_wq   = (const float*)d_in[15];
    const float* tp_bq   = (const float*)d_in[16];
    const float* tp_wk   = (const float*)d_in[17];
    const float* tp_bk   = (const float*)d_in[18];
    const float* tp_wv   = (const float*)d_in[19];
    const float* tp_bv   = (const float*)d_in[20];
    const float* tp_wo   = (const float*)d_in[21];
    const float* tp_bo   = (const float*)d_in[22];
    const float* c_wqkv  = (const float*)d_in[23];
    const float* c_bqkv  = (const float*)d_in[24];
    const float* c_wo    = (const float*)d_in[25];
    const float* c_bo    = (const float*)d_in[26];
    const float* m_w1    = (const float*)d_in[27];
    const float* m_b1    = (const float*)d_in[28];
    const float* m_w2    = (const float*)d_in[29];
    const float* m_b2    = (const float*)d_in[30];
    float* out = (float*)d_out;

    float* ws = (float*)d_ws;
    size_t o = 0;
    float* part  = ws + o; o += (size_t)BB * 8 * DD;
    int*   idx   = (int*)(ws + o); o += 16;
    float* tpb   = ws + o; o += 4 * 2304;                     // packed temporal bias
    float* x1b   = ws + o; o += (size_t)4096 * DD;            // f32 (x + fused)
    u16* xnb   = (u16*)(ws + o); o += (size_t)4096 * DD / 2;  // LN out (tiled bf16)
    u16* tmp1b = (u16*)(ws + o); o += (size_t)4096 * DD / 2;  // attn out (tiled)
    u16* tmp2b = (u16*)(ws + o); o += (size_t)4096 * DD / 2;  // LN for mlp (tiled)
    u16* soutb = (u16*)(ws + o); o += (size_t)4096 * DD / 2;  // spatial_out (tiled)
    u16* toutb = (u16*)(ws + o); o += (size_t)4096 * DD / 2;  // temporal_out (tiled)
    u16* qkvb  = (u16*)(ws + o); o += (size_t)4096 * 2304 / 2;// q|k|v row-major bf16
    u16* yb    = (u16*)(ws + o); o += (size_t)4096 * 3072 / 2;// mlp hidden (tiled)
    u16* wpool = (u16*)(ws + o); o += (size_t)CUM10 / 2;      // bf16 weights (tiled)

    u16* w_sp_qkv = wpool;
    u16* w_sp_wo  = wpool + CUM1;
    u16* w_tp_qkv = wpool + CUM2;   // interleaved [e][2304][768] tiled
    u16* w_tp_o   = wpool + CUM5;
    u16* w_c_qkv  = wpool + CUM6;
    u16* w_c_wo   = wpool + CUM7;
    u16* w_m1     = wpool + CUM8;
    u16* w_m2     = wpool + CUM9;

    int* idx_s = idx;
    int* idx_t = idx + BB;

    const long long sTD  = (long long)TT * DD;       // 512*768
    const long long sT3D = (long long)TT * 3 * DD;   // 512*2304
    const long long sT4D = (long long)TT * 4 * DD;   // 512*3072
    const float qk_scale = 1.0f / sqrtf((float)HDIM);

    // ---- weight convert (f32 -> bf16 tiled) + temporal bias pack ----
    cvt_kernel<<<(int)((CUM10 / 8 + 255) / 256), 256, 0, stream>>>(
        sp_wqkv, sp_wo, tp_wq, tp_wk, tp_wv, tp_wo, c_wqkv, c_wo, m_w1, m_w2, wpool);
    pack_tpb_kernel<<<36, 256, 0, stream>>>(tp_bq, tp_bk, tp_bv, tpb);

    // ---- router ----
    mean_part_kernel<<<dim3(BB, 3, 8), 256, 0, stream>>>(x, part);
    router_kernel<<<BB, 128, 0, stream>>>(part, rw1, rb1, rw2, rb2, idx);

    // ---- spatial branch ----
    ln_kernel<<<4096, 256, 0, stream>>>(x, gs, bs, xnb);
    // qkv = xn @ sp_wqkv[idx_s]^T + sp_bqkv[idx_s]  -> row-major for attn
    run_gemm2(stream, xnb, sTD, w_sp_qkv, idx_s, 3 * DDDD,
              qkvb, sT3D, 3 * DD, sp_bqkv, 3 * DD, nullptr, 0, 0,
              0, 3 * DD, DD, 1, 0);
    attn_kernel<<<dim3(TT / 64, BB * HH), 256, 0, stream>>>(qkvb, tmp1b, 0, qk_scale);
    // spatial_out = O @ sp_wo[idx_s]^T + sp_bo[idx_s]  -> tiled
    run_gemm2(stream, tmp1b, sTD, w_sp_wo, idx_s, DDDD,
              soutb, sTD, DD, sp_bo, DD, nullptr, 0, 0,
              0, DD, DD, 2, 0);

    // ---- temporal branch ----
    ln_kernel<<<4096, 256, 0, stream>>>(x, gt, btt, xnb);
    run_gemm2(stream, xnb, sTD, w_tp_qkv, idx_t, 3 * DDDD,
              qkvb, sT3D, 3 * DD, tpb, 3 * DD, nullptr, 0, 0,
              0, 3 * DD, DD, 1, 0);
    attn_kernel<<<dim3(TT / 64, BB * HH), 256, 0, stream>>>(qkvb, tmp1b, 1, qk_scale);
    // temporal_out = xt + O @ tp_wo[idx_t]^T + tp_bo[idx_t]  (tiled, tiled resid)
    run_gemm2(stream, tmp1b, sTD, w_tp_o, idx_t, DDDD,
              toutb, sTD, DD, tp_bo, DD, xnb, sTD, DD,
              0, DD, DD, 2, 2);

    // ---- cross attention ----
    run_gemm2(stream, soutb, sTD, w_c_qkv, nullptr, 0,
              qkvb, sT3D, 3 * DD, c_bqkv, 0, nullptr, 0, 0,
              0, DD, DD, 1, 0);
    // rows 768..2303 of c_wqkv = tiles 6.. -> offset 6*(768/8)*1024 = DDDD elems
    run_gemm2(stream, toutb, sTD, w_c_qkv + DDDD, nullptr, 0,
              qkvb + DD, sT3D, 3 * DD, c_bqkv + DD, 0, nullptr, 0, 0,
              0, 2 * DD, DD, 1, 0);
    attn_kernel<<<dim3(TT / 64, BB * HH), 256, 0, stream>>>(qkvb, tmp1b, 0, qk_scale);
    // x1 = x + (fused_attn @ cross_wo^T + cross_bo)   (f32 out, f32 resid)
    run_gemm2(stream, tmp1b, sTD, w_c_wo, nullptr, 0,
              x1b, sTD, DD, c_bo, 0, x, sTD, DD,
              0, DD, DD, 0, 1);

    // ---- MLP ----
    ln_kernel<<<4096, 256, 0, stream>>>(x1b, gm, bm, tmp2b);
    // y = gelu(ln @ mlp_w1^T + b1) -> tiled bf16
    run_gemm2(stream, tmp2b, sTD, w_m1, nullptr, 0,
              yb, sT4D, 4 * DD, m_b1, 0, nullptr, 0, 0,
              1, 4 * DD, DD, 2, 0);
    // out = x1 + y @ mlp_w2^T + b2   (f32 out, f32 resid)
    run_gemm2(stream, yb, sT4D, w_m2, nullptr, 0,
              out, sTD, DD, m_b2, 0, x1b, sTD, DD,
              0, DD, 4 * DD, 0, 1);
}